// Round 3
// baseline (605.794 us; speedup 1.0000x reference)
//
#include <hip/hip_runtime.h>

#define AS1 __attribute__((address_space(1)))
#define AS3 __attribute__((address_space(3)))

typedef __bf16 bf16_t;
typedef __bf16 bf16x8 __attribute__((ext_vector_type(8)));
typedef __bf16 bf16x4 __attribute__((ext_vector_type(4)));
typedef float  floatx4 __attribute__((ext_vector_type(4)));
typedef unsigned int uint2_ __attribute__((ext_vector_type(2)));
typedef unsigned int uint4_ __attribute__((ext_vector_type(4)));

#define MFMA_BF16(a, b, c) __builtin_amdgcn_mfma_f32_16x16x32_bf16(a, b, c, 0, 0, 0)

static constexpr int T_  = 2048;
static constexpr int D_  = 3584;
static constexpr int NH_ = 28;   // query heads
static constexpr int KV_ = 4;    // kv heads
static constexpr int H_  = 128;  // head dim
static constexpr int NW_ = 36;   // 28 q + 4 k + 4 v projection heads

// LOG2E folded into the q-scale so softmax runs in the exp2 domain
#define QSCALE 0.12754245778287616f   /* H^-0.5 * log2(e) */

// ---------------------------------------------------------------------------
// Elementwise fp32 -> bf16 convert (8 elems/thread)
// ---------------------------------------------------------------------------
__global__ void convert_f32_bf16(const float* __restrict__ src, bf16_t* __restrict__ dst) {
    const long i = (long)(blockIdx.x * blockDim.x + threadIdx.x) * 8;
    float4 a = ((const float4*)(src + i))[0];
    float4 b = ((const float4*)(src + i))[1];
    bf16x8 o = {(bf16_t)a.x, (bf16_t)a.y, (bf16_t)a.z, (bf16_t)a.w,
                (bf16_t)b.x, (bf16_t)b.y, (bf16_t)b.z, (bf16_t)b.w};
    *(bf16x8*)(dst + i) = o;
}

// ---------------------------------------------------------------------------
// 64x64-tile fp32 -> bf16 transpose, vectorized: dst[c][r] = (bf16)src[r][c]
// ---------------------------------------------------------------------------
__global__ __launch_bounds__(256) void transpose64_f32_bf16(const float* __restrict__ src,
                                                            bf16_t* __restrict__ dst,
                                                            int R, int C, long sStride, long dStride) {
    __shared__ bf16_t t[64][68];
    src += (long)blockIdx.z * sStride;
    dst += (long)blockIdx.z * dStride;
    const int tid = threadIdx.x;
    const int r0 = blockIdx.y * 64, c0 = blockIdx.x * 64;
#pragma unroll
    for (int p = 0; p < 4; p++) {
        const int row = (tid >> 4) + p * 16, col4 = tid & 15;
        float4 v = *(const float4*)(src + (long)(r0 + row) * C + c0 + col4 * 4);
        bf16x4 b = {(bf16_t)v.x, (bf16_t)v.y, (bf16_t)v.z, (bf16_t)v.w};
        *(bf16x4*)&t[row][col4 * 4] = b;
    }
    __syncthreads();
#pragma unroll
    for (int p = 0; p < 2; p++) {
        const int cc = (tid >> 3) + p * 32, k = tid & 7;
        bf16x8 o;
#pragma unroll
        for (int j = 0; j < 8; j++) o[j] = t[8 * k + j][cc];
        *(bf16x8*)(dst + (long)(c0 + cc) * R + r0 + 8 * k) = o;
    }
}

// ---------------------------------------------------------------------------
// Small 32x32 bf16 transpose (used for V^T only, 2 MB)
// ---------------------------------------------------------------------------
__global__ void transpose32_bf16(const bf16_t* __restrict__ src, bf16_t* __restrict__ dst,
                                 int R, int C, long sStride, long dStride) {
    __shared__ bf16_t tile[32][33];
    src += (long)blockIdx.z * sStride;
    dst += (long)blockIdx.z * dStride;
    const int tx = threadIdx.x & 31, ty = threadIdx.x >> 5;
    const int r0 = blockIdx.y * 32, c0 = blockIdx.x * 32;
#pragma unroll
    for (int i = 0; i < 4; i++) {
        int rr = ty + i * 8;
        tile[rr][tx] = src[(long)(r0 + rr) * C + c0 + tx];
    }
    __syncthreads();
#pragma unroll
    for (int i = 0; i < 4; i++) {
        int cc = ty + i * 8;
        dst[(long)(c0 + cc) * R + r0 + tx] = tile[tx][cc];
    }
}

// ---------------------------------------------------------------------------
// m97-style 128x128 GEMM core: C = A[128 x K] * Bt[128 x K]^T, fp32 acc.
// ---------------------------------------------------------------------------
__device__ __forceinline__ void gemm_core_128x128(const bf16_t* __restrict__ Arows, int lda,
                                                  const bf16_t* __restrict__ Brows, int ldb,
                                                  int K, floatx4 acc[4][4]) {
    __shared__ bf16_t As[128 * 32];
    __shared__ bf16_t Bs[128 * 32];
    const int tid = threadIdx.x;
    const int w = tid >> 6, l = tid & 63;
    const int lr = l >> 2, lc = l & 3;
    const int m16 = l & 15, quad = l >> 4;
    const int wr = w >> 1, wc = w & 1;
#pragma unroll
    for (int i = 0; i < 4; i++)
#pragma unroll
        for (int j = 0; j < 4; j++) acc[i][j] = (floatx4){0.f, 0.f, 0.f, 0.f};

    for (int kt = 0; kt < K; kt += 32) {
        __syncthreads();
#pragma unroll
        for (int is = 0; is < 2; is++) {
            const int row = 32 * w + 16 * is + lr;
            __builtin_amdgcn_global_load_lds((const AS1 void*)(Arows + (long)row * lda + kt + lc * 8),
                                             (AS3 void*)(As + row * 32 + lc * 8), 16, 0, 0);
            __builtin_amdgcn_global_load_lds((const AS1 void*)(Brows + (long)row * ldb + kt + lc * 8),
                                             (AS3 void*)(Bs + row * 32 + lc * 8), 16, 0, 0);
        }
        __syncthreads();
        bf16x8 af[4], bfr[4];
#pragma unroll
        for (int i = 0; i < 4; i++)
            af[i] = *(const bf16x8*)(As + (64 * wr + 16 * i + m16) * 32 + quad * 8);
#pragma unroll
        for (int j = 0; j < 4; j++)
            bfr[j] = *(const bf16x8*)(Bs + (64 * wc + 16 * j + m16) * 32 + quad * 8);
#pragma unroll
        for (int i = 0; i < 4; i++)
#pragma unroll
            for (int j = 0; j < 4; j++) acc[i][j] = MFMA_BF16(af[i], bfr[j], acc[i][j]);
    }
}

// QKV projection: out[hd][t][h] = x[t][:] . w[hd][:][h] + bias[hd][h]
__global__ __launch_bounds__(256) void gemm_qkv_kernel(const bf16_t* __restrict__ X,
                                                       const bf16_t* __restrict__ Wt,
                                                       const float* __restrict__ bq,
                                                       const float* __restrict__ bk,
                                                       const float* __restrict__ bv,
                                                       bf16_t* __restrict__ out) {
    const int mt = blockIdx.x, hd = blockIdx.y;
    const float* bias = hd < NH_ ? bq + hd * H_
                                 : (hd < NH_ + KV_ ? bk + (hd - NH_) * H_ : bv + (hd - NH_ - KV_) * H_);
    floatx4 acc[4][4];
    gemm_core_128x128(X + (long)mt * 128 * D_, D_, Wt + (long)hd * H_ * D_, D_, D_, acc);
    const int l = threadIdx.x & 63, w = threadIdx.x >> 6;
    const int m16 = l & 15, quad = l >> 4, wr = w >> 1, wc = w & 1;
    bf16_t* C = out + (long)hd * T_ * H_ + (long)mt * 128 * H_;
#pragma unroll
    for (int j = 0; j < 4; j++) {
        const int col = 64 * wc + 16 * j + m16;
        const float bb = bias[col];
#pragma unroll
        for (int i = 0; i < 4; i++) {
            const int row = 64 * wr + 16 * i + quad * 4;
#pragma unroll
            for (int r = 0; r < 4; r++) C[(row + r) * H_ + col] = (bf16_t)(acc[i][j][r] + bb);
        }
    }
}

// Output projection: out[t][d] = ctx[t][:] . woT[d][:]  (fp32 output)
__global__ __launch_bounds__(256) void gemm_out_kernel(const bf16_t* __restrict__ A,
                                                       const bf16_t* __restrict__ Bt,
                                                       float* __restrict__ Cg) {
    const int mt = blockIdx.x, nt = blockIdx.y;
    floatx4 acc[4][4];
    gemm_core_128x128(A + (long)mt * 128 * D_, D_, Bt + (long)nt * 128 * D_, D_, D_, acc);
    const int l = threadIdx.x & 63, w = threadIdx.x >> 6;
    const int m16 = l & 15, quad = l >> 4, wr = w >> 1, wc = w & 1;
    float* C = Cg + (long)mt * 128 * D_ + nt * 128;
#pragma unroll
    for (int j = 0; j < 4; j++) {
        const int col = 64 * wc + 16 * j + m16;
#pragma unroll
        for (int i = 0; i < 4; i++) {
            const int row = 64 * wr + 16 * i + quad * 4;
#pragma unroll
            for (int r = 0; r < 4; r++) C[(long)(row + r) * D_ + col] = acc[i][j][r];
        }
    }
}

// ---------------------------------------------------------------------------
// In-place RoPE on q (heads 0..27, scaled by H^-0.5 * log2e) and k (28..31)
// ---------------------------------------------------------------------------
__global__ void rope_kernel(bf16_t* __restrict__ qkv, const int* __restrict__ pos) {
    const int idx = blockIdx.x * blockDim.x + threadIdx.x;
    const int h = idx & 63;
    const int t = (idx >> 6) & (T_ - 1);
    const int hd = idx >> 17;
    if (hd >= NH_ + KV_) return;
    bf16_t* p = qkv + ((long)hd * T_ + t) * H_;
    const float x1 = (float)p[h], x2 = (float)p[h + 64];
    const float inv = expf(-(float)h * (13.815510557964274f / 64.f));
    const float ang = (float)pos[t] * inv;
    float s, c;
    sincosf(ang, &s, &c);
    float o1 = x1 * c - x2 * s;
    float o2 = x2 * c + x1 * s;
    if (hd < NH_) { o1 *= QSCALE; o2 *= QSCALE; }   // softmax runs in exp2 domain
    p[h] = (bf16_t)o1;
    p[h + 64] = (bf16_t)o2;
}

// ---------------------------------------------------------------------------
// Flash attention, R7: no split-s, no barriers, no LDS staging.
//  * Grid = (16 q-tiles, 28 heads) = 448 blocks — ALL co-resident from t=0
//    (capacity >= 2 blocks/CU): no scheduling churn, no dispatch-order tail.
//    R0-R2 post-mortems: loop-internal changes (conflicts, barriers, dbuf)
//    all nulled; the machine was ~65% idle on block churn + 4-wave lockstep.
//  * Each wave independently owns 32 q-rows and the full causal s-range with
//    per-wave early exit; ZERO __syncthreads in the kernel.
//  * K/V fragments read directly from global: per-head K/V = 1 MB, L2/L3-
//    resident (Common-mistake #7: LDS-staging cache-fit data is overhead).
//    Kills the LDS-pipe serialization (was 32 ds_read_b128/wave-iter) and
//    moves the traffic to the idle VMEM pipe.
//  * Split-s combine deleted: no Opart (-36.9 MB wr, -36.7 MB rd), no ml,
//    no combine_kernel; O normalized in-wave and written straight to ctx.
//  * Defer-max (T13, THR=8 in exp2 domain): skip rescale chain when no row
//    max grew; P bounded by 2^8, fp32 li absorbs it.
// ---------------------------------------------------------------------------
__global__ __launch_bounds__(256) void attn_kernel(const bf16_t* __restrict__ qkv,
                                                   const bf16_t* __restrict__ vT,
                                                   bf16_t* __restrict__ ctx) {
    __shared__ bf16_t smem[4 * 32 * 128];        // per-wave-private 8 KB epilogue

    const int qb = blockIdx.x, n = blockIdx.y;
    const int kvh = n / 7;
    const bf16_t* Q  = qkv + (long)n * T_ * H_;
    const bf16_t* Kg = qkv + (long)(NH_ + kvh) * T_ * H_;
    const bf16_t* Vg = vT  + (long)kvh * H_ * T_;   // [h][t]

    const int tid = threadIdx.x, w = tid >> 6, l = tid & 63;
    const int m16 = l & 15, quad = l >> 4;
    const int q0 = qb * 128 + w * 32;

    bf16x8 qf[2][4];
#pragma unroll
    for (int qt = 0; qt < 2; qt++)
#pragma unroll
        for (int kk = 0; kk < 4; kk++)
            qf[qt][kk] = *(const bf16x8*)(Q + (long)(q0 + qt * 16 + m16) * H_ + kk * 32 + quad * 8);

    floatx4 ot[2][8];
#pragma unroll
    for (int qt = 0; qt < 2; qt++)
#pragma unroll
        for (int ht = 0; ht < 8; ht++) ot[qt][ht] = (floatx4){0.f, 0.f, 0.f, 0.f};
    float mi[2] = {-1e30f, -1e30f}, li[2] = {0.f, 0.f};

    // shuffle source lanes for the P redistribution (loop-invariant)
    const int s0 = m16 + ((quad & 1) << 5);
    const int s1 = s0 + 16;
    const bool hiq = (quad & 2) != 0;

    const int sbE = (q0 + 95) >> 6;              // causal end for rows q0..q0+31

    for (int sb = 0; sb < sbE; sb++) {
        const bf16_t* Kb = Kg + (long)sb * 64 * H_;
        const bf16_t* Vb = Vg + sb * 64;

        // S^T[s][q] = sum_h K[s][h] Q[q][h]; K fragments straight from L2
        floatx4 stv[2][4];
        __builtin_amdgcn_s_setprio(1);
#pragma unroll
        for (int ts = 0; ts < 4; ts++) {
            bf16x8 kf[4];
#pragma unroll
            for (int kk = 0; kk < 4; kk++)
                kf[kk] = *(const bf16x8*)(Kb + (long)(16 * ts + m16) * H_ + kk * 32 + quad * 8);
#pragma unroll
            for (int qt = 0; qt < 2; qt++) {
                floatx4 c = (floatx4){0.f, 0.f, 0.f, 0.f};
#pragma unroll
                for (int kk = 0; kk < 4; kk++) c = MFMA_BF16(kf[kk], qf[qt][kk], c);
                stv[qt][ts] = c;
            }
        }
        __builtin_amdgcn_s_setprio(0);

        // online softmax (exp2 domain) with defer-max; pack P to bf16 words
        unsigned int W[2][4][2];
        const bool need_mask = (sb * 64 + 63) > q0;
#pragma unroll
        for (int qt = 0; qt < 2; qt++) {
            const int qg = q0 + qt * 16 + m16;
            if (need_mask) {
#pragma unroll
                for (int ts = 0; ts < 4; ts++)
#pragma unroll
                    for (int r = 0; r < 4; r++) {
                        const int sg = sb * 64 + ts * 16 + quad * 4 + r;
                        if (sg > qg) stv[qt][ts][r] = -1e30f;
                    }
            }
            float mx = -1e30f;
#pragma unroll
            for (int ts = 0; ts < 4; ts++)
#pragma unroll
                for (int r = 0; r < 4; r++) mx = fmaxf(mx, stv[qt][ts][r]);
            mx = fmaxf(mx, __shfl_xor(mx, 16));
            mx = fmaxf(mx, __shfl_xor(mx, 32));
            float mn = mi[qt];
            if (__any(mx > mi[qt] + 8.f)) {      // wave-uniform rescale branch
                mn = fmaxf(mi[qt], mx);
                const float alpha = exp2f(mi[qt] - mn);
                mi[qt] = mn;
                li[qt] *= alpha;
#pragma unroll
                for (int ht = 0; ht < 8; ht++) ot[qt][ht] *= alpha;
            }
            float rs = 0.f;
#pragma unroll
            for (int ts = 0; ts < 4; ts++) {
                const float p0 = exp2f(stv[qt][ts][0] - mn);
                const float p1 = exp2f(stv[qt][ts][1] - mn);
                const float p2 = exp2f(stv[qt][ts][2] - mn);
                const float p3 = exp2f(stv[qt][ts][3] - mn);
                rs += p0 + p1 + p2 + p3;
                bf16x4 pv = {(bf16_t)p0, (bf16_t)p1, (bf16_t)p2, (bf16_t)p3};
                uint2_ u = __builtin_bit_cast(uint2_, pv);
                W[qt][ts][0] = u.x;
                W[qt][ts][1] = u.y;
            }
            rs += __shfl_xor(rs, 16);
            rs += __shfl_xor(rs, 32);
            li[qt] += rs;
        }

        // O^T[h][q] += sum_s V^T[h][s] P^T[s][q]; P redistributed via shfl,
        // V fragments straight from L2 (vT rows).
#pragma unroll
        for (int ck = 0; ck < 2; ck++) {
            bf16x8 pf[2];
#pragma unroll
            for (int qt = 0; qt < 2; qt++) {
                const unsigned a0 = W[qt][2 * ck][0], a1 = W[qt][2 * ck][1];
                const unsigned b0 = W[qt][2 * ck + 1][0], b1 = W[qt][2 * ck + 1][1];
                unsigned pw0, pw1, pw2, pw3;
                { const unsigned xa = __shfl((int)a0, s0), xb = __shfl((int)b0, s0); pw0 = hiq ? xb : xa; }
                { const unsigned xa = __shfl((int)a1, s0), xb = __shfl((int)b1, s0); pw1 = hiq ? xb : xa; }
                { const unsigned xa = __shfl((int)a0, s1), xb = __shfl((int)b0, s1); pw2 = hiq ? xb : xa; }
                { const unsigned xa = __shfl((int)a1, s1), xb = __shfl((int)b1, s1); pw3 = hiq ? xb : xa; }
                uint4_ pv4 = {pw0, pw1, pw2, pw3};
                pf[qt] = __builtin_bit_cast(bf16x8, pv4);
            }
            __builtin_amdgcn_s_setprio(1);
#pragma unroll
            for (int ht = 0; ht < 8; ht++) {
                bf16x8 vf = *(const bf16x8*)(Vb + (long)(16 * ht + m16) * T_ + ck * 32 + quad * 8);
                ot[0][ht] = MFMA_BF16(vf, pf[0], ot[0][ht]);
                ot[1][ht] = MFMA_BF16(vf, pf[1], ot[1][ht]);
            }
            __builtin_amdgcn_s_setprio(0);
        }
    }

    // Epilogue (per-wave private, no barriers): normalize, transpose O^T -> O
    // via swizzled 8 KB LDS region, write straight to ctx[t][n*H+h].
    const float inv0 = 1.f / li[0], inv1 = 1.f / li[1];
    bf16_t* Oq = smem + w * (32 * 128);
#pragma unroll
    for (int qt = 0; qt < 2; qt++) {
        const float inv = qt ? inv1 : inv0;
        const int r = qt * 16 + m16;
#pragma unroll
        for (int ht = 0; ht < 8; ht++) {
            bf16x4 v = {(bf16_t)(ot[qt][ht][0] * inv), (bf16_t)(ot[qt][ht][1] * inv),
                        (bf16_t)(ot[qt][ht][2] * inv), (bf16_t)(ot[qt][ht][3] * inv)};
            const int chunk = (2 * ht + (quad >> 1)) ^ (r & 7);
            *(bf16x4*)((char*)Oq + r * 256 + (chunk << 4) + ((quad & 1) << 3)) = v;
        }
    }
    {
        const int qrow = l >> 1, hf = l & 1;
        bf16_t* dst = ctx + (long)(q0 + qrow) * (NH_ * H_) + n * H_ + hf * 64;
#pragma unroll
        for (int j = 0; j < 8; j++) {
            const bf16x8 o = *(const bf16x8*)((char*)Oq + qrow * 256 +
                                              ((((hf << 3) + j) ^ (qrow & 7)) << 4));
            *(bf16x8*)(dst + j * 8) = o;
        }
    }
}

// ---------------------------------------------------------------------------
extern "C" void kernel_launch(void* const* d_in, const int* in_sizes, int n_in,
                              void* d_out, int out_size, void* d_ws, size_t ws_size,
                              hipStream_t stream) {
    const float* x  = (const float*)d_in[0];
    const int*   ps = (const int*)d_in[1];
    const float* wq = (const float*)d_in[2];
    const float* bq = (const float*)d_in[3];
    const float* wk = (const float*)d_in[4];
    const float* bk = (const float*)d_in[5];
    const float* wv = (const float*)d_in[6];
    const float* bv = (const float*)d_in[7];
    const float* wo = (const float*)d_in[8];
    float* out = (float*)d_out;

    bf16_t* xb  = (bf16_t*)d_ws;                 // [2048][3584]    x in bf16
    bf16_t* wt  = xb + (long)T_ * D_;            // [36][128][3584] transposed qkv weights
    bf16_t* woT = wt + (long)NW_ * H_ * D_;      // [3584][3584]    woT[d][n*H+h]
    bf16_t* qkv = woT + (long)D_ * D_;           // [36][2048][128] projections
    bf16_t* vT  = qkv + (long)NW_ * T_ * H_;     // [4][128][2048]  V transposed
    bf16_t* ctx = vT + (long)KV_ * H_ * T_;      // [2048][3584]    attention output (bf16)

    const long whd = (long)D_ * H_;
    convert_f32_bf16<<<((long)T_ * D_ / 8 + 255) / 256, 256, 0, stream>>>(x, xb);
    transpose64_f32_bf16<<<dim3(H_ / 64, D_ / 64, NH_), 256, 0, stream>>>(wq, wt, D_, H_, whd, whd);
    transpose64_f32_bf16<<<dim3(H_ / 64, D_ / 64, KV_), 256, 0, stream>>>(wk, wt + (long)NH_ * whd, D_, H_, whd, whd);
    transpose64_f32_bf16<<<dim3(H_ / 64, D_ / 64, KV_), 256, 0, stream>>>(wv, wt + (long)(NH_ + KV_) * whd, D_, H_, whd, whd);
    transpose64_f32_bf16<<<dim3(D_ / 64, D_ / 64, 1), 256, 0, stream>>>(wo, woT, D_, D_, 0, 0);

    gemm_qkv_kernel<<<dim3(T_ / 128, NW_), 256, 0, stream>>>(xb, wt, bq, bk, bv, qkv);
    rope_kernel<<<(32 * T_ * 64) / 256, 256, 0, stream>>>(qkv, ps);
    transpose32_bf16<<<dim3(H_ / 32, T_ / 32, KV_), 256, 0, stream>>>(qkv + (long)(NH_ + KV_) * T_ * H_, vT,
                                                                      T_, H_, (long)T_ * H_, (long)T_ * H_);
    attn_kernel<<<dim3(T_ / 128, NH_), 256, 0, stream>>>(qkv, vT, ctx);
    gemm_out_kernel<<<dim3(T_ / 128, D_ / 128), 256, 0, stream>>>(ctx, woT, out);
}

// Round 6
// 563.315 us; speedup vs baseline: 1.0754x; 1.0754x over previous
//
#include <hip/hip_runtime.h>

#define AS1 __attribute__((address_space(1)))
#define AS3 __attribute__((address_space(3)))

typedef __bf16 bf16_t;
typedef __bf16 bf16x8 __attribute__((ext_vector_type(8)));
typedef __bf16 bf16x4 __attribute__((ext_vector_type(4)));
typedef float  floatx4 __attribute__((ext_vector_type(4)));
typedef unsigned int uint2_ __attribute__((ext_vector_type(2)));
typedef unsigned int uint4_ __attribute__((ext_vector_type(4)));

#define MFMA_BF16(a, b, c) __builtin_amdgcn_mfma_f32_16x16x32_bf16(a, b, c, 0, 0, 0)

static constexpr int T_  = 2048;
static constexpr int D_  = 3584;
static constexpr int NH_ = 28;   // query heads
static constexpr int KV_ = 4;    // kv heads
static constexpr int H_  = 128;  // head dim
static constexpr int NW_ = 36;   // 28 q + 4 k + 4 v projection heads
static constexpr int FPH_ = 40;  // split-s work items per head: sum_qb ceil((qb+1)/4)

#define WAITV(n) asm volatile("s_waitcnt vmcnt(" #n ")" ::: "memory")

// ---------------------------------------------------------------------------
// Elementwise fp32 -> bf16 convert (8 elems/thread)
// ---------------------------------------------------------------------------
__global__ void convert_f32_bf16(const float* __restrict__ src, bf16_t* __restrict__ dst) {
    const long i = (long)(blockIdx.x * blockDim.x + threadIdx.x) * 8;
    float4 a = ((const float4*)(src + i))[0];
    float4 b = ((const float4*)(src + i))[1];
    bf16x8 o = {(bf16_t)a.x, (bf16_t)a.y, (bf16_t)a.z, (bf16_t)a.w,
                (bf16_t)b.x, (bf16_t)b.y, (bf16_t)b.z, (bf16_t)b.w};
    *(bf16x8*)(dst + i) = o;
}

// ---------------------------------------------------------------------------
// 64x64-tile fp32 -> bf16 transpose, vectorized: dst[c][r] = (bf16)src[r][c]
// ---------------------------------------------------------------------------
__global__ __launch_bounds__(256) void transpose64_f32_bf16(const float* __restrict__ src,
                                                            bf16_t* __restrict__ dst,
                                                            int R, int C, long sStride, long dStride) {
    __shared__ bf16_t t[64][68];
    src += (long)blockIdx.z * sStride;
    dst += (long)blockIdx.z * dStride;
    const int tid = threadIdx.x;
    const int r0 = blockIdx.y * 64, c0 = blockIdx.x * 64;
#pragma unroll
    for (int p = 0; p < 4; p++) {
        const int row = (tid >> 4) + p * 16, col4 = tid & 15;
        float4 v = *(const float4*)(src + (long)(r0 + row) * C + c0 + col4 * 4);
        bf16x4 b = {(bf16_t)v.x, (bf16_t)v.y, (bf16_t)v.z, (bf16_t)v.w};
        *(bf16x4*)&t[row][col4 * 4] = b;
    }
    __syncthreads();
#pragma unroll
    for (int p = 0; p < 2; p++) {
        const int cc = (tid >> 3) + p * 32, k = tid & 7;
        bf16x8 o;
#pragma unroll
        for (int j = 0; j < 8; j++) o[j] = t[8 * k + j][cc];
        *(bf16x8*)(dst + (long)(c0 + cc) * R + r0 + 8 * k) = o;
    }
}

// ---------------------------------------------------------------------------
// Small 32x32 bf16 transpose (used for V^T only, 2 MB)
// ---------------------------------------------------------------------------
__global__ void transpose32_bf16(const bf16_t* __restrict__ src, bf16_t* __restrict__ dst,
                                 int R, int C, long sStride, long dStride) {
    __shared__ bf16_t tile[32][33];
    src += (long)blockIdx.z * sStride;
    dst += (long)blockIdx.z * dStride;
    const int tx = threadIdx.x & 31, ty = threadIdx.x >> 5;
    const int r0 = blockIdx.y * 32, c0 = blockIdx.x * 32;
#pragma unroll
    for (int i = 0; i < 4; i++) {
        int rr = ty + i * 8;
        tile[rr][tx] = src[(long)(r0 + rr) * C + c0 + tx];
    }
    __syncthreads();
#pragma unroll
    for (int i = 0; i < 4; i++) {
        int cc = ty + i * 8;
        dst[(long)(c0 + cc) * R + r0 + tx] = tile[tx][cc];
    }
}

// ---------------------------------------------------------------------------
// R8 GEMM: BM=256, BN=128, BK=32, 512 threads (8 waves, 4Mx2N, 64x64/wave).
// 3-deep LDS ring (72 KB), counted vmcnt(3) + raw s_barrier (never drain to 0
// in the main loop — T3/T4), pair-XOR swizzled LDS via pre-swizzled
// global_load_lds sources (G21), s_setprio around MFMA (T5).
//
// Swizzle unit: 2 rows = 128 B = 8 chunks of 16 B. Logical chunk within pair
// L = (row&1)*4 + colchunk; physical slot P = L ^ (pair&7). Involution; each
// 16-lane read phase hits each bank group at most 2x (free, m136).
//
// vmcnt ledger (loads/thread/step = 3: 2 A + 1 B):
//   prologue stages s=0,1 -> 6 outstanding
//   step s: WAITV(3) [s's 3 done] -> barrier -> ds_read slot s%3 ->
//           stage s+2 into slot (s+2)%3 (= slot of s-1, consumed; barrier-
//           protected) -> MFMA.  Peel: s=110 WAITV(3), s=111 WAITV(0).
// Deadlock-free: uniform control flow, equal barrier counts, monotone waits.
// ---------------------------------------------------------------------------
__device__ __forceinline__ void stage_tileA(const bf16_t* __restrict__ g, int kt,
                                            bf16_t* sl, int tid) {
#pragma unroll
    for (int c = 0; c < 2; c++) {
        const int chunk = c * 512 + tid;      // 1024 chunks: 256 rows x 4
        const int pair = chunk >> 3, P = chunk & 7;
        const int L = P ^ (pair & 7);
        const int row = (pair << 1) | (L >> 2);
        const int cc = L & 3;
        __builtin_amdgcn_global_load_lds((const AS1 void*)(g + (long)row * D_ + kt + cc * 8),
                                         (AS3 void*)(sl + chunk * 8), 16, 0, 0);
    }
}

__device__ __forceinline__ void stage_tileB(const bf16_t* __restrict__ g, int kt,
                                            bf16_t* sl, int tid) {
    const int chunk = tid;                    // 512 chunks: 128 rows x 4
    const int pair = chunk >> 3, P = chunk & 7;
    const int L = P ^ (pair & 7);
    const int row = (pair << 1) | (L >> 2);
    const int cc = L & 3;
    __builtin_amdgcn_global_load_lds((const AS1 void*)(g + (long)row * D_ + kt + cc * 8),
                                     (AS3 void*)(sl + chunk * 8), 16, 0, 0);
}

__device__ __forceinline__ void gstep(const bf16_t* __restrict__ As, const bf16_t* __restrict__ Bs,
                                      bf16_t* Asn, bf16_t* Bsn,
                                      const bf16_t* __restrict__ Ag, const bf16_t* __restrict__ Bg,
                                      int ktn, bool do_stage, int tid,
                                      int wr, int wn, int m16, int quad,
                                      floatx4 acc[4][4]) {
    bf16x8 af[4], bfv[4];
#pragma unroll
    for (int i = 0; i < 4; i++) {
        const int rr = wr * 64 + i * 16 + m16;
        const int L = ((rr & 1) << 2) | quad;
        af[i] = *(const bf16x8*)(As + ((rr >> 1) << 6) + ((L ^ ((rr >> 1) & 7)) << 3));
    }
#pragma unroll
    for (int j = 0; j < 4; j++) {
        const int rr = wn * 64 + j * 16 + m16;
        const int L = ((rr & 1) << 2) | quad;
        bfv[j] = *(const bf16x8*)(Bs + ((rr >> 1) << 6) + ((L ^ ((rr >> 1) & 7)) << 3));
    }
    if (do_stage) {
        stage_tileA(Ag, ktn, Asn, tid);
        stage_tileB(Bg, ktn, Bsn, tid);
    }
    __builtin_amdgcn_s_setprio(1);
#pragma unroll
    for (int i = 0; i < 4; i++)
#pragma unroll
        for (int j = 0; j < 4; j++) acc[i][j] = MFMA_BF16(af[i], bfv[j], acc[i][j]);
    __builtin_amdgcn_s_setprio(0);
}

#define GSTEP(AS_, BS_, ASN_, BSN_, STG_)                                         \
    WAITV(3); __builtin_amdgcn_s_barrier();                                       \
    gstep(AS_, BS_, ASN_, BSN_, Ag, Bg, kts, STG_, tid, wr, wn, m16, quad, acc);  \
    kts += 32;

template<bool QKV>
__global__ __launch_bounds__(512, 2) void gemm256_kernel(const bf16_t* __restrict__ A,
                                                         const bf16_t* __restrict__ Bt,
                                                         const float* __restrict__ bq,
                                                         const float* __restrict__ bk,
                                                         const float* __restrict__ bv,
                                                         bf16_t* __restrict__ outb,
                                                         float* __restrict__ outf,
                                                         int NT) {
    __shared__ bf16_t As0[256 * 32], As1[256 * 32], As2[256 * 32];
    __shared__ bf16_t Bs0[128 * 32], Bs1[128 * 32], Bs2[128 * 32];

    const int nwg = gridDim.x;
    const int lin = blockIdx.x;
    const int wg = (lin & 7) * (nwg >> 3) + (lin >> 3);   // XCD-chunked (nwg%8==0)
    const int mt = wg / NT, nt = wg % NT;

    const bf16_t* Ag = A + (long)mt * 256 * D_;
    const bf16_t* Bg = Bt + (long)nt * 128 * D_;

    const int tid = threadIdx.x, w = tid >> 6, l = tid & 63;
    const int m16 = l & 15, quad = l >> 4;
    const int wr = w >> 1, wn = w & 1;

    floatx4 acc[4][4];
#pragma unroll
    for (int i = 0; i < 4; i++)
#pragma unroll
        for (int j = 0; j < 4; j++) acc[i][j] = (floatx4){0.f, 0.f, 0.f, 0.f};

    // prologue: stage steps 0,1 (6 loads/thread outstanding)
    stage_tileA(Ag, 0, As0, tid);  stage_tileB(Bg, 0, Bs0, tid);
    stage_tileA(Ag, 32, As1, tid); stage_tileB(Bg, 32, Bs1, tid);
    int kts = 64;                                  // kt of next stage (step s+2)

#pragma unroll 1
    for (int g = 0; g < 36; g++) {                 // 108 steps; keep rolled (I-cache)
        GSTEP(As0, Bs0, As2, Bs2, true)
        GSTEP(As1, Bs1, As0, Bs0, true)
        GSTEP(As2, Bs2, As1, Bs1, true)
    }
    // peel s=108..111 (slots 0,1,2,0; stages for 110,111 only)
    GSTEP(As0, Bs0, As2, Bs2, true)                // s=108, stages step 110
    GSTEP(As1, Bs1, As0, Bs0, true)                // s=109, stages step 111
    WAITV(3); __builtin_amdgcn_s_barrier();
    gstep(As2, Bs2, As0, Bs0, Ag, Bg, 0, false, tid, wr, wn, m16, quad, acc);   // s=110
    WAITV(0); __builtin_amdgcn_s_barrier();
    gstep(As0, Bs0, As1, Bs1, Ag, Bg, 0, false, tid, wr, wn, m16, quad, acc);   // s=111

    // epilogue
    if (QKV) {
        const int hd = nt;    // BN=128 == H: one head per col-tile
        const float* bias = hd < NH_ ? bq + hd * H_
                                     : (hd < NH_ + KV_ ? bk + (hd - NH_) * H_
                                                       : bv + (hd - NH_ - KV_) * H_);
        bf16_t* C = outb + (long)hd * T_ * H_ + (long)(mt * 256) * H_;
#pragma unroll
        for (int j = 0; j < 4; j++) {
            const int col = wn * 64 + j * 16 + m16;
            const float bb = bias[col];
#pragma unroll
            for (int i = 0; i < 4; i++) {
                const int row = wr * 64 + i * 16 + quad * 4;
#pragma unroll
                for (int r = 0; r < 4; r++) C[(long)(row + r) * H_ + col] = (bf16_t)(acc[i][j][r] + bb);
            }
        }
    } else {
        float* C = outf + (long)(mt * 256) * D_ + nt * 128;
#pragma unroll
        for (int j = 0; j < 4; j++) {
            const int col = wn * 64 + j * 16 + m16;
#pragma unroll
            for (int i = 0; i < 4; i++) {
                const int row = wr * 64 + i * 16 + quad * 4;
#pragma unroll
                for (int r = 0; r < 4; r++) C[(long)(row + r) * D_ + col] = acc[i][j][r];
            }
        }
    }
}

// ---------------------------------------------------------------------------
// In-place RoPE on q (heads 0..27, scaled by H^-0.5) and k (heads 28..31)
// ---------------------------------------------------------------------------
__global__ void rope_kernel(bf16_t* __restrict__ qkv, const int* __restrict__ pos) {
    const int idx = blockIdx.x * blockDim.x + threadIdx.x;
    const int h = idx & 63;
    const int t = (idx >> 6) & (T_ - 1);
    const int hd = idx >> 17;
    if (hd >= NH_ + KV_) return;
    bf16_t* p = qkv + ((long)hd * T_ + t) * H_;
    const float x1 = (float)p[h], x2 = (float)p[h + 64];
    const float inv = expf(-(float)h * (13.815510557964274f / 64.f));
    const float ang = (float)pos[t] * inv;
    float s, c;
    sincosf(ang, &s, &c);
    float o1 = x1 * c - x2 * s;
    float o2 = x2 * c + x1 * s;
    if (hd < NH_) { o1 *= 0.08838834764831845f; o2 *= 0.08838834764831845f; }
    p[h] = (bf16_t)o1;
    p[h + 64] = (bf16_t)o2;
}

// ---------------------------------------------------------------------------
// Split-s flash attention — restored R1 config (best measured: 124.0 us).
// K/V staged via global_load_lds with pre-swizzled sources; P in-register.
// ---------------------------------------------------------------------------
__global__ __launch_bounds__(256) void attn_kernel(const bf16_t* __restrict__ qkv,
                                                   const bf16_t* __restrict__ vT,
                                                   bf16_t* __restrict__ Opart,
                                                   float* __restrict__ ml) {
    __shared__ bf16_t smem[64 * 128 + 128 * 64];   // Ks[64][128] + Vs[128][64], swizzled
    bf16_t* Ks = smem;
    bf16_t* Vs = smem + 64 * 128;

    const int n = blockIdx.y;
    int qb = 0, rem = blockIdx.x;
    while (true) { int ch = (qb + 4) >> 2; if (rem < ch) break; rem -= ch; qb++; }
    const long pidx = (long)n * FPH_ + blockIdx.x;

    const int kvh = n / 7;
    const bf16_t* Q  = qkv + (long)n * T_ * H_;
    const bf16_t* Kg = qkv + (long)(NH_ + kvh) * T_ * H_;
    const bf16_t* Vg = vT + (long)kvh * H_ * T_;  // [h][t]

    const int tid = threadIdx.x, w = tid >> 6, l = tid & 63;
    const int m16 = l & 15, quad = l >> 4;
    const int q0 = qb * 128 + w * 32;

    int kOff[4], vOff[4];
#pragma unroll
    for (int i = 0; i < 4; i++) {
        const int ck_ = i * 256 + tid;           // K: 64 rows x 16 chunks
        const int kr = ck_ >> 4, kc = ck_ & 15;
        kOff[i] = kr * H_ + ((kc ^ (kr & 7)) << 3);
        const int vr = ck_ >> 3, vc = ck_ & 7;   // V: 128 rows x 8 chunks
        vOff[i] = vr * T_ + ((vc ^ (vr & 7)) << 3);
    }

    bf16x8 qf[2][4];
#pragma unroll
    for (int qt = 0; qt < 2; qt++)
#pragma unroll
        for (int kk = 0; kk < 4; kk++)
            qf[qt][kk] = *(const bf16x8*)(Q + (long)(q0 + qt * 16 + m16) * H_ + kk * 32 + quad * 8);

    floatx4 ot[2][8];
#pragma unroll
    for (int qt = 0; qt < 2; qt++)
#pragma unroll
        for (int ht = 0; ht < 8; ht++) ot[qt][ht] = (floatx4){0.f, 0.f, 0.f, 0.f};
    float mi[2] = {-1e30f, -1e30f}, li[2] = {0.f, 0.f};

    const int sb0 = rem * 8;
    const int sbE = min(sb0 + 8, 2 * qb + 2);

    const int s0 = m16 + ((quad & 1) << 5);
    const int s1 = s0 + 16;
    const bool hi = (quad & 2) != 0;

    for (int sb = sb0; sb < sbE; sb++) {
        __syncthreads();
        {
            const long kBase = (long)sb * 64 * H_;
            const int  vBase = sb * 64;
#pragma unroll
            for (int i = 0; i < 4; i++)
                __builtin_amdgcn_global_load_lds((const AS1 void*)(Kg + kBase + kOff[i]),
                                                 (AS3 void*)(Ks + (i * 256 + tid) * 8), 16, 0, 0);
#pragma unroll
            for (int i = 0; i < 4; i++)
                __builtin_amdgcn_global_load_lds((const AS1 void*)(Vg + vBase + vOff[i]),
                                                 (AS3 void*)(Vs + (i * 256 + tid) * 8), 16, 0, 0);
        }
        __syncthreads();

        floatx4 stv[2][4];
#pragma unroll
        for (int ts = 0; ts < 4; ts++) {
            bf16x8 kf[4];
#pragma unroll
            for (int kk = 0; kk < 4; kk++)
                kf[kk] = *(const bf16x8*)(Ks + (16 * ts + m16) * 128 +
                                          ((((kk << 2) + quad) ^ (m16 & 7)) << 3));
#pragma unroll
            for (int qt = 0; qt < 2; qt++) {
                floatx4 c = (floatx4){0.f, 0.f, 0.f, 0.f};
#pragma unroll
                for (int kk = 0; kk < 4; kk++) c = MFMA_BF16(kf[kk], qf[qt][kk], c);
                stv[qt][ts] = c;
            }
        }

        unsigned int W[2][4][2];
        const bool need_mask = (sb * 64 + 63) > q0;
#pragma unroll
        for (int qt = 0; qt < 2; qt++) {
            const int qg = q0 + qt * 16 + m16;
            if (need_mask) {
#pragma unroll
                for (int ts = 0; ts < 4; ts++)
#pragma unroll
                    for (int r = 0; r < 4; r++) {
                        const int sg = sb * 64 + ts * 16 + quad * 4 + r;
                        if (sg > qg) stv[qt][ts][r] = -1e30f;
                    }
            }
            float mx = -1e30f;
#pragma unroll
            for (int ts = 0; ts < 4; ts++)
#pragma unroll
                for (int r = 0; r < 4; r++) mx = fmaxf(mx, stv[qt][ts][r]);
            mx = fmaxf(mx, __shfl_xor(mx, 16));
            mx = fmaxf(mx, __shfl_xor(mx, 32));
            const float mn = fmaxf(mi[qt], mx);
            const float alpha = __expf(mi[qt] - mn);
            mi[qt] = mn;
            float rs = 0.f;
#pragma unroll
            for (int ts = 0; ts < 4; ts++) {
                const float p0 = __expf(stv[qt][ts][0] - mn);
                const float p1 = __expf(stv[qt][ts][1] - mn);
                const float p2 = __expf(stv[qt][ts][2] - mn);
                const float p3 = __expf(stv[qt][ts][3] - mn);
                rs += p0 + p1 + p2 + p3;
                bf16x4 pv = {(bf16_t)p0, (bf16_t)p1, (bf16_t)p2, (bf16_t)p3};
                uint2_ u = __builtin_bit_cast(uint2_, pv);
                W[qt][ts][0] = u.x;
                W[qt][ts][1] = u.y;
            }
            rs += __shfl_xor(rs, 16);
            rs += __shfl_xor(rs, 32);
            li[qt] = li[qt] * alpha + rs;
#pragma unroll
            for (int ht = 0; ht < 8; ht++) ot[qt][ht] *= alpha;
        }

#pragma unroll
        for (int ck = 0; ck < 2; ck++) {
            bf16x8 pf[2];
#pragma unroll
            for (int qt = 0; qt < 2; qt++) {
                const unsigned a0 = W[qt][2 * ck][0], a1 = W[qt][2 * ck][1];
                const unsigned b0 = W[qt][2 * ck + 1][0], b1 = W[qt][2 * ck + 1][1];
                unsigned pw0, pw1, pw2, pw3;
                { const unsigned xa = __shfl((int)a0, s0), xb = __shfl((int)b0, s0); pw0 = hi ? xb : xa; }
                { const unsigned xa = __shfl((int)a1, s0), xb = __shfl((int)b1, s0); pw1 = hi ? xb : xa; }
                { const unsigned xa = __shfl((int)a0, s1), xb = __shfl((int)b0, s1); pw2 = hi ? xb : xa; }
                { const unsigned xa = __shfl((int)a1, s1), xb = __shfl((int)b1, s1); pw3 = hi ? xb : xa; }
                uint4_ pv4 = {pw0, pw1, pw2, pw3};
                pf[qt] = __builtin_bit_cast(bf16x8, pv4);
            }
#pragma unroll
            for (int ht = 0; ht < 8; ht++) {
                bf16x8 vf = *(const bf16x8*)(Vs + (16 * ht + m16) * 64 +
                                             ((((ck << 2) + quad) ^ (m16 & 7)) << 3));
                ot[0][ht] = MFMA_BF16(vf, pf[0], ot[0][ht]);
                ot[1][ht] = MFMA_BF16(vf, pf[1], ot[1][ht]);
            }
        }
    }

#pragma unroll
    for (int qt = 0; qt < 2; qt++) {
        if (quad == 0) {
            const int row = w * 32 + qt * 16 + m16;
            ml[pidx * 256 + row] = mi[qt];
            ml[pidx * 256 + 128 + row] = li[qt];
        }
    }

    __syncthreads();
    const float inv0 = 1.f / li[0], inv1 = 1.f / li[1];
    bf16_t* Oq = smem + w * (32 * 128);
#pragma unroll
    for (int qt = 0; qt < 2; qt++) {
        const float inv = qt ? inv1 : inv0;
        const int r = qt * 16 + m16;
#pragma unroll
        for (int ht = 0; ht < 8; ht++) {
            bf16x4 v = {(bf16_t)(ot[qt][ht][0] * inv), (bf16_t)(ot[qt][ht][1] * inv),
                        (bf16_t)(ot[qt][ht][2] * inv), (bf16_t)(ot[qt][ht][3] * inv)};
            const int chunk = (2 * ht + (quad >> 1)) ^ (r & 7);
            *(bf16x4*)((char*)Oq + r * 256 + (chunk << 4) + ((quad & 1) << 3)) = v;
        }
    }
    __syncthreads();
    {
        const int qrow = l >> 1, hf = l & 1;
        const int qloc = w * 32 + qrow;
        bf16_t* dst = Opart + (pidx * 128 + qloc) * 128 + hf * 64;
#pragma unroll
        for (int j = 0; j < 8; j++) {
            const bf16x8 o = *(const bf16x8*)((char*)Oq + qrow * 256 +
                                              ((((hf << 3) + j) ^ (qrow & 7)) << 4));
            *(bf16x8*)(dst + j * 8) = o;
        }
    }
}

// ---------------------------------------------------------------------------
// Combine partial attention chunks: ctx[t][n*H+h] = sum_c w_c * O_c
// ---------------------------------------------------------------------------
__global__ __launch_bounds__(256) void combine_kernel(const bf16_t* __restrict__ Opart,
                                                      const float* __restrict__ ml,
                                                      bf16_t* __restrict__ ctx) {
    const int qb = blockIdx.x, n = blockIdx.y;
    const int C = (qb + 4) >> 2;
    int f0 = 0;
    for (int i = 0; i < qb; i++) f0 += (i + 4) >> 2;
    const int tid = threadIdx.x;
    const int qrow = tid >> 1, half = tid & 1;
    const long pb = (long)n * FPH_ + f0;

    float m[4], lv[4], wv[4];
    float M = -1e30f;
    for (int c = 0; c < C; c++) {
        m[c] = ml[(pb + c) * 256 + qrow];
        lv[c] = ml[(pb + c) * 256 + 128 + qrow];
        M = fmaxf(M, m[c]);
    }
    float wsum = 0.f;
    for (int c = 0; c < C; c++) { wv[c] = lv[c] * __expf(m[c] - M); wsum += wv[c]; }
    const float invw = 1.f / wsum;
    for (int c = 0; c < C; c++) wv[c] *= invw;

    bf16_t* dst = ctx + ((long)(qb * 128 + qrow)) * (NH_ * H_) + n * H_ + half * 64;
#pragma unroll
    for (int j = 0; j < 8; j++) {
        float acc[8] = {0, 0, 0, 0, 0, 0, 0, 0};
        for (int c = 0; c < C; c++) {
            bf16x8 v = *(const bf16x8*)(Opart + ((pb + c) * 128 + qrow) * 128 + half * 64 + j * 8);
#pragma unroll
            for (int e = 0; e < 8; e++) acc[e] += wv[c] * (float)v[e];
        }
        bf16x8 o;
#pragma unroll
        for (int e = 0; e < 8; e++) o[e] = (bf16_t)acc[e];
        *(bf16x8*)(dst + j * 8) = o;
    }
}

// ---------------------------------------------------------------------------
extern "C" void kernel_launch(void* const* d_in, const int* in_sizes, int n_in,
                              void* d_out, int out_size, void* d_ws, size_t ws_size,
                              hipStream_t stream) {
    const float* x  = (const float*)d_in[0];
    const int*   ps = (const int*)d_in[1];
    const float* wq = (const float*)d_in[2];
    const float* bq = (const float*)d_in[3];
    const float* wk = (const float*)d_in[4];
    const float* bk = (const float*)d_in[5];
    const float* wv = (const float*)d_in[6];
    const float* bv = (const float*)d_in[7];
    const float* wo = (const float*)d_in[8];
    float* out = (float*)d_out;

    bf16_t* xb  = (bf16_t*)d_ws;                 // [2048][3584]    x in bf16
    bf16_t* wt  = xb + (long)T_ * D_;            // [36][128][3584] transposed qkv weights
    bf16_t* woT = wt + (long)NW_ * H_ * D_;      // [3584][3584]    woT[d][n*H+h]
    bf16_t* qkv = woT + (long)D_ * D_;           // [36][2048][128] projections
    bf16_t* vT  = qkv + (long)NW_ * T_ * H_;     // [4][128][2048]  V transposed
    bf16_t* ctx = vT + (long)KV_ * H_ * T_;      // [2048][3584]    attention output (bf16)
    // partials alias xb+wt (dead after gemm_qkv): 36.7 MB + 1.15 MB < 47.7 MB
    bf16_t* Opart = (bf16_t*)d_ws;               // [28*40][128][128] bf16
    float*  ml    = (float*)((char*)d_ws + (long)NH_ * FPH_ * 128 * 128 * 2);  // [28*40][2][128]

    const long whd = (long)D_ * H_;
    convert_f32_bf16<<<((long)T_ * D_ / 8 + 255) / 256, 256, 0, stream>>>(x, xb);
    transpose64_f32_bf16<<<dim3(H_ / 64, D_ / 64, NH_), 256, 0, stream>>>(wq, wt, D_, H_, whd, whd);
    transpose64_f32_bf16<<<dim3(H_ / 64, D_ / 64, KV_), 256, 0, stream>>>(wk, wt + (long)NH_ * whd, D_, H_, whd, whd);
    transpose64_f32_bf16<<<dim3(H_ / 64, D_ / 64, KV_), 256, 0, stream>>>(wv, wt + (long)(NH_ + KV_) * whd, D_, H_, whd, whd);
    transpose64_f32_bf16<<<dim3(D_ / 64, D_ / 64, 1), 256, 0, stream>>>(wo, woT, D_, D_, 0, 0);

    gemm256_kernel<true><<<dim3(T_ / 256 * NW_), 512, 0, stream>>>(xb, wt, bq, bk, bv, qkv, nullptr, NW_);
    rope_kernel<<<(32 * T_ * 64) / 256, 256, 0, stream>>>(qkv, ps);
    transpose32_bf16<<<dim3(H_ / 32, T_ / 32, KV_), 256, 0, stream>>>(qkv + (long)(NH_ + KV_) * T_ * H_, vT,
                                                                      T_, H_, (long)T_ * H_, (long)T_ * H_);
    attn_kernel<<<dim3(FPH_, NH_), 256, 0, stream>>>(qkv, vT, Opart, ml);
    combine_kernel<<<dim3(T_ / 128, NH_), 256, 0, stream>>>(Opart, ml, ctx);
    gemm256_kernel<false><<<dim3(T_ / 256 * (D_ / 128)), 512, 0, stream>>>(ctx, woT, nullptr, nullptr, nullptr,
                                                                           nullptr, out, D_ / 128);
}

// Round 7
// 528.164 us; speedup vs baseline: 1.1470x; 1.0666x over previous
//
#include <hip/hip_runtime.h>

#define AS1 __attribute__((address_space(1)))
#define AS3 __attribute__((address_space(3)))

typedef __bf16 bf16_t;
typedef __bf16 bf16x8 __attribute__((ext_vector_type(8)));
typedef __bf16 bf16x4 __attribute__((ext_vector_type(4)));
typedef float  floatx4 __attribute__((ext_vector_type(4)));
typedef unsigned int uint2_ __attribute__((ext_vector_type(2)));
typedef unsigned int uint4_ __attribute__((ext_vector_type(4)));

#define MFMA_BF16(a, b, c) __builtin_amdgcn_mfma_f32_16x16x32_bf16(a, b, c, 0, 0, 0)

static constexpr int T_  = 2048;
static constexpr int D_  = 3584;
static constexpr int NH_ = 28;   // query heads
static constexpr int KV_ = 4;    // kv heads
static constexpr int H_  = 128;  // head dim
static constexpr int NW_ = 36;   // 28 q + 4 k + 4 v projection heads
static constexpr int FPH_ = 40;  // split-s work items per head: sum_qb ceil((qb+1)/4)

#define WAITV(n) asm volatile("s_waitcnt vmcnt(" #n ")" ::: "memory")

// ---------------------------------------------------------------------------
// Elementwise fp32 -> bf16 convert (8 elems/thread)
// ---------------------------------------------------------------------------
__global__ void convert_f32_bf16(const float* __restrict__ src, bf16_t* __restrict__ dst) {
    const long i = (long)(blockIdx.x * blockDim.x + threadIdx.x) * 8;
    float4 a = ((const float4*)(src + i))[0];
    float4 b = ((const float4*)(src + i))[1];
    bf16x8 o = {(bf16_t)a.x, (bf16_t)a.y, (bf16_t)a.z, (bf16_t)a.w,
                (bf16_t)b.x, (bf16_t)b.y, (bf16_t)b.z, (bf16_t)b.w};
    *(bf16x8*)(dst + i) = o;
}

// ---------------------------------------------------------------------------
// 64x64-tile fp32 -> bf16 transpose, vectorized: dst[c][r] = (bf16)src[r][c]
// ---------------------------------------------------------------------------
__global__ __launch_bounds__(256) void transpose64_f32_bf16(const float* __restrict__ src,
                                                            bf16_t* __restrict__ dst,
                                                            int R, int C, long sStride, long dStride) {
    __shared__ bf16_t t[64][68];
    src += (long)blockIdx.z * sStride;
    dst += (long)blockIdx.z * dStride;
    const int tid = threadIdx.x;
    const int r0 = blockIdx.y * 64, c0 = blockIdx.x * 64;
#pragma unroll
    for (int p = 0; p < 4; p++) {
        const int row = (tid >> 4) + p * 16, col4 = tid & 15;
        float4 v = *(const float4*)(src + (long)(r0 + row) * C + c0 + col4 * 4);
        bf16x4 b = {(bf16_t)v.x, (bf16_t)v.y, (bf16_t)v.z, (bf16_t)v.w};
        *(bf16x4*)&t[row][col4 * 4] = b;
    }
    __syncthreads();
#pragma unroll
    for (int p = 0; p < 2; p++) {
        const int cc = (tid >> 3) + p * 32, k = tid & 7;
        bf16x8 o;
#pragma unroll
        for (int j = 0; j < 8; j++) o[j] = t[8 * k + j][cc];
        *(bf16x8*)(dst + (long)(c0 + cc) * R + r0 + 8 * k) = o;
    }
}

// ---------------------------------------------------------------------------
// Small 32x32 bf16 transpose (used for V^T only, 2 MB)
// ---------------------------------------------------------------------------
__global__ void transpose32_bf16(const bf16_t* __restrict__ src, bf16_t* __restrict__ dst,
                                 int R, int C, long sStride, long dStride) {
    __shared__ bf16_t tile[32][33];
    src += (long)blockIdx.z * sStride;
    dst += (long)blockIdx.z * dStride;
    const int tx = threadIdx.x & 31, ty = threadIdx.x >> 5;
    const int r0 = blockIdx.y * 32, c0 = blockIdx.x * 32;
#pragma unroll
    for (int i = 0; i < 4; i++) {
        int rr = ty + i * 8;
        tile[rr][tx] = src[(long)(r0 + rr) * C + c0 + tx];
    }
    __syncthreads();
#pragma unroll
    for (int i = 0; i < 4; i++) {
        int cc = ty + i * 8;
        dst[(long)(c0 + cc) * R + r0 + tx] = tile[tx][cc];
    }
}

// ---------------------------------------------------------------------------
// R9 GEMM: BM=BN=128, BK=32, 256 threads (4 waves, 2Mx2N, 64x64/wave).
// Ring-3 LDS (48 KB -> 3 blocks/CU co-resident), counted WAITV(4) + raw
// s_barrier (one barrier/step, never drain to 0 in-loop), pair-XOR swizzle
// via pre-swizzled global_load_lds sources, s_setprio around MFMA.
//
// R6 post-mortem: 256x128 grid 288 = 36 blocks/XCD on 32 CUs -> 2x imbalance
// (dur 2x ideal, MfmaUtil 19.5 = half of per-gen ~39, occupancy 13 = half of
// 28). 128^2 gives grid 576/448 -> 75%/87.5% CU-time utilization AND 3/CU
// co-residency (the m97-measured 912-TF regime).
//
// vmcnt ledger (4 loads/wave/step: 2 A + 2 B):
//   prologue stages s=0,1 -> 8 outstanding
//   step s: WAITV(4) [s's 4 done] -> barrier -> ds_read slot s%3 ->
//           stage s+2 into slot (s+2)%3 (consumed by step s-1; the barrier
//           orders reads-before-overwrite) -> MFMA.
//   peel: s=110 WAITV(4), s=111 WAITV(0).
// ---------------------------------------------------------------------------
__device__ __forceinline__ void stage_t128(const bf16_t* __restrict__ g, int kt,
                                           bf16_t* sl, int tid) {
#pragma unroll
    for (int c = 0; c < 2; c++) {
        const int chunk = c * 256 + tid;      // 512 chunks: 128 rows x 4
        const int pair = chunk >> 3, P = chunk & 7;
        const int L = P ^ (pair & 7);
        const int row = (pair << 1) | (L >> 2);
        const int cc = L & 3;
        __builtin_amdgcn_global_load_lds((const AS1 void*)(g + (long)row * D_ + kt + cc * 8),
                                         (AS3 void*)(sl + chunk * 8), 16, 0, 0);
    }
}

__device__ __forceinline__ void gstep(const bf16_t* __restrict__ As, const bf16_t* __restrict__ Bs,
                                      bf16_t* Asn, bf16_t* Bsn,
                                      const bf16_t* __restrict__ Ag, const bf16_t* __restrict__ Bg,
                                      int ktn, bool do_stage, int tid,
                                      int wr, int wn, int m16, int quad,
                                      floatx4 acc[4][4]) {
    bf16x8 af[4], bfv[4];
#pragma unroll
    for (int i = 0; i < 4; i++) {
        const int rr = wr * 64 + i * 16 + m16;
        const int L = ((rr & 1) << 2) | quad;
        af[i] = *(const bf16x8*)(As + ((rr >> 1) << 6) + ((L ^ ((rr >> 1) & 7)) << 3));
    }
#pragma unroll
    for (int j = 0; j < 4; j++) {
        const int rr = wn * 64 + j * 16 + m16;
        const int L = ((rr & 1) << 2) | quad;
        bfv[j] = *(const bf16x8*)(Bs + ((rr >> 1) << 6) + ((L ^ ((rr >> 1) & 7)) << 3));
    }
    if (do_stage) {
        stage_t128(Ag, ktn, Asn, tid);
        stage_t128(Bg, ktn, Bsn, tid);
    }
    __builtin_amdgcn_s_setprio(1);
#pragma unroll
    for (int i = 0; i < 4; i++)
#pragma unroll
        for (int j = 0; j < 4; j++) acc[i][j] = MFMA_BF16(af[i], bfv[j], acc[i][j]);
    __builtin_amdgcn_s_setprio(0);
}

#define GSTEP(AS_, BS_, ASN_, BSN_, STG_)                                         \
    WAITV(4); __builtin_amdgcn_s_barrier();                                       \
    gstep(AS_, BS_, ASN_, BSN_, Ag, Bg, kts, STG_, tid, wr, wn, m16, quad, acc);  \
    kts += 32;

template<bool QKV>
__global__ __launch_bounds__(256, 3) void gemm128_kernel(const bf16_t* __restrict__ A,
                                                         const bf16_t* __restrict__ Bt,
                                                         const float* __restrict__ bq,
                                                         const float* __restrict__ bk,
                                                         const float* __restrict__ bv,
                                                         bf16_t* __restrict__ outb,
                                                         float* __restrict__ outf,
                                                         int NT) {
    __shared__ bf16_t As0[128 * 32], As1[128 * 32], As2[128 * 32];
    __shared__ bf16_t Bs0[128 * 32], Bs1[128 * 32], Bs2[128 * 32];

    const int nwg = gridDim.x;
    const int lin = blockIdx.x;
    const int wg = (lin & 7) * (nwg >> 3) + (lin >> 3);   // XCD-chunked (nwg%8==0)
    const int mt = wg / NT, nt = wg % NT;

    const bf16_t* Ag = A + (long)mt * 128 * D_;
    const bf16_t* Bg = Bt + (long)nt * 128 * D_;

    const int tid = threadIdx.x, w = tid >> 6, l = tid & 63;
    const int m16 = l & 15, quad = l >> 4;
    const int wr = w >> 1, wn = w & 1;

    floatx4 acc[4][4];
#pragma unroll
    for (int i = 0; i < 4; i++)
#pragma unroll
        for (int j = 0; j < 4; j++) acc[i][j] = (floatx4){0.f, 0.f, 0.f, 0.f};

    // prologue: stage steps 0,1 (8 load-instructions/wave outstanding)
    stage_t128(Ag, 0, As0, tid);  stage_t128(Bg, 0, Bs0, tid);
    stage_t128(Ag, 32, As1, tid); stage_t128(Bg, 32, Bs1, tid);
    int kts = 64;                                  // kt of next stage (step s+2)

#pragma unroll 1
    for (int g = 0; g < 36; g++) {                 // s = 0..107
        GSTEP(As0, Bs0, As2, Bs2, true)
        GSTEP(As1, Bs1, As0, Bs0, true)
        GSTEP(As2, Bs2, As1, Bs1, true)
    }
    GSTEP(As0, Bs0, As2, Bs2, true)                // s=108, stages s110 (kt 3520)
    GSTEP(As1, Bs1, As0, Bs0, true)                // s=109, stages s111 (kt 3552)
    WAITV(4); __builtin_amdgcn_s_barrier();
    gstep(As2, Bs2, As0, Bs0, Ag, Bg, 0, false, tid, wr, wn, m16, quad, acc);   // s=110
    WAITV(0); __builtin_amdgcn_s_barrier();
    gstep(As0, Bs0, As1, Bs1, Ag, Bg, 0, false, tid, wr, wn, m16, quad, acc);   // s=111

    // epilogue
    if (QKV) {
        const int hd = nt;    // BN=128 == H: one head per col-tile
        const float* bias = hd < NH_ ? bq + hd * H_
                                     : (hd < NH_ + KV_ ? bk + (hd - NH_) * H_
                                                       : bv + (hd - NH_ - KV_) * H_);
        bf16_t* C = outb + (long)hd * T_ * H_ + (long)(mt * 128) * H_;
#pragma unroll
        for (int j = 0; j < 4; j++) {
            const int col = wn * 64 + j * 16 + m16;
            const float bb = bias[col];
#pragma unroll
            for (int i = 0; i < 4; i++) {
                const int row = wr * 64 + i * 16 + quad * 4;
#pragma unroll
                for (int r = 0; r < 4; r++) C[(long)(row + r) * H_ + col] = (bf16_t)(acc[i][j][r] + bb);
            }
        }
    } else {
        float* C = outf + (long)(mt * 128) * D_ + nt * 128;
#pragma unroll
        for (int j = 0; j < 4; j++) {
            const int col = wn * 64 + j * 16 + m16;
#pragma unroll
            for (int i = 0; i < 4; i++) {
                const int row = wr * 64 + i * 16 + quad * 4;
#pragma unroll
                for (int r = 0; r < 4; r++) C[(long)(row + r) * D_ + col] = acc[i][j][r];
            }
        }
    }
}

// ---------------------------------------------------------------------------
// In-place RoPE on q (heads 0..27, scaled by H^-0.5) and k (heads 28..31)
// ---------------------------------------------------------------------------
__global__ void rope_kernel(bf16_t* __restrict__ qkv, const int* __restrict__ pos) {
    const int idx = blockIdx.x * blockDim.x + threadIdx.x;
    const int h = idx & 63;
    const int t = (idx >> 6) & (T_ - 1);
    const int hd = idx >> 17;
    if (hd >= NH_ + KV_) return;
    bf16_t* p = qkv + ((long)hd * T_ + t) * H_;
    const float x1 = (float)p[h], x2 = (float)p[h + 64];
    const float inv = expf(-(float)h * (13.815510557964274f / 64.f));
    const float ang = (float)pos[t] * inv;
    float s, c;
    sincosf(ang, &s, &c);
    float o1 = x1 * c - x2 * s;
    float o2 = x2 * c + x1 * s;
    if (hd < NH_) { o1 *= 0.08838834764831845f; o2 *= 0.08838834764831845f; }
    p[h] = (bf16_t)o1;
    p[h + 64] = (bf16_t)o2;
}

// ---------------------------------------------------------------------------
// Split-s flash attention — R1 config (best measured: 124.0 us). Untouched.
// ---------------------------------------------------------------------------
__global__ __launch_bounds__(256) void attn_kernel(const bf16_t* __restrict__ qkv,
                                                   const bf16_t* __restrict__ vT,
                                                   bf16_t* __restrict__ Opart,
                                                   float* __restrict__ ml) {
    __shared__ bf16_t smem[64 * 128 + 128 * 64];   // Ks[64][128] + Vs[128][64], swizzled
    bf16_t* Ks = smem;
    bf16_t* Vs = smem + 64 * 128;

    const int n = blockIdx.y;
    int qb = 0, rem = blockIdx.x;
    while (true) { int ch = (qb + 4) >> 2; if (rem < ch) break; rem -= ch; qb++; }
    const long pidx = (long)n * FPH_ + blockIdx.x;

    const int kvh = n / 7;
    const bf16_t* Q  = qkv + (long)n * T_ * H_;
    const bf16_t* Kg = qkv + (long)(NH_ + kvh) * T_ * H_;
    const bf16_t* Vg = vT + (long)kvh * H_ * T_;  // [h][t]

    const int tid = threadIdx.x, w = tid >> 6, l = tid & 63;
    const int m16 = l & 15, quad = l >> 4;
    const int q0 = qb * 128 + w * 32;

    int kOff[4], vOff[4];
#pragma unroll
    for (int i = 0; i < 4; i++) {
        const int ck_ = i * 256 + tid;           // K: 64 rows x 16 chunks
        const int kr = ck_ >> 4, kc = ck_ & 15;
        kOff[i] = kr * H_ + ((kc ^ (kr & 7)) << 3);
        const int vr = ck_ >> 3, vc = ck_ & 7;   // V: 128 rows x 8 chunks
        vOff[i] = vr * T_ + ((vc ^ (vr & 7)) << 3);
    }

    bf16x8 qf[2][4];
#pragma unroll
    for (int qt = 0; qt < 2; qt++)
#pragma unroll
        for (int kk = 0; kk < 4; kk++)
            qf[qt][kk] = *(const bf16x8*)(Q + (long)(q0 + qt * 16 + m16) * H_ + kk * 32 + quad * 8);

    floatx4 ot[2][8];
#pragma unroll
    for (int qt = 0; qt < 2; qt++)
#pragma unroll
        for (int ht = 0; ht < 8; ht++) ot[qt][ht] = (floatx4){0.f, 0.f, 0.f, 0.f};
    float mi[2] = {-1e30f, -1e30f}, li[2] = {0.f, 0.f};

    const int sb0 = rem * 8;
    const int sbE = min(sb0 + 8, 2 * qb + 2);

    const int s0 = m16 + ((quad & 1) << 5);
    const int s1 = s0 + 16;
    const bool hi = (quad & 2) != 0;

    for (int sb = sb0; sb < sbE; sb++) {
        __syncthreads();
        {
            const long kBase = (long)sb * 64 * H_;
            const int  vBase = sb * 64;
#pragma unroll
            for (int i = 0; i < 4; i++)
                __builtin_amdgcn_global_load_lds((const AS1 void*)(Kg + kBase + kOff[i]),
                                                 (AS3 void*)(Ks + (i * 256 + tid) * 8), 16, 0, 0);
#pragma unroll
            for (int i = 0; i < 4; i++)
                __builtin_amdgcn_global_load_lds((const AS1 void*)(Vg + vBase + vOff[i]),
                                                 (AS3 void*)(Vs + (i * 256 + tid) * 8), 16, 0, 0);
        }
        __syncthreads();

        floatx4 stv[2][4];
#pragma unroll
        for (int ts = 0; ts < 4; ts++) {
            bf16x8 kf[4];
#pragma unroll
            for (int kk = 0; kk < 4; kk++)
                kf[kk] = *(const bf16x8*)(Ks + (16 * ts + m16) * 128 +
                                          ((((kk << 2) + quad) ^ (m16 & 7)) << 3));
#pragma unroll
            for (int qt = 0; qt < 2; qt++) {
                floatx4 c = (floatx4){0.f, 0.f, 0.f, 0.f};
#pragma unroll
                for (int kk = 0; kk < 4; kk++) c = MFMA_BF16(kf[kk], qf[qt][kk], c);
                stv[qt][ts] = c;
            }
        }

        unsigned int W[2][4][2];
        const bool need_mask = (sb * 64 + 63) > q0;
#pragma unroll
        for (int qt = 0; qt < 2; qt++) {
            const int qg = q0 + qt * 16 + m16;
            if (need_mask) {
#pragma unroll
                for (int ts = 0; ts < 4; ts++)
#pragma unroll
                    for (int r = 0; r < 4; r++) {
                        const int sg = sb * 64 + ts * 16 + quad * 4 + r;
                        if (sg > qg) stv[qt][ts][r] = -1e30f;
                    }
            }
            float mx = -1e30f;
#pragma unroll
            for (int ts = 0; ts < 4; ts++)
#pragma unroll
                for (int r = 0; r < 4; r++) mx = fmaxf(mx, stv[qt][ts][r]);
            mx = fmaxf(mx, __shfl_xor(mx, 16));
            mx = fmaxf(mx, __shfl_xor(mx, 32));
            const float mn = fmaxf(mi[qt], mx);
            const float alpha = __expf(mi[qt] - mn);
            mi[qt] = mn;
            float rs = 0.f;
#pragma unroll
            for (int ts = 0; ts < 4; ts++) {
                const float p0 = __expf(stv[qt][ts][0] - mn);
                const float p1 = __expf(stv[qt][ts][1] - mn);
                const float p2 = __expf(stv[qt][ts][2] - mn);
                const float p3 = __expf(stv[qt][ts][3] - mn);
                rs += p0 + p1 + p2 + p3;
                bf16x4 pv = {(bf16_t)p0, (bf16_t)p1, (bf16_t)p2, (bf16_t)p3};
                uint2_ u = __builtin_bit_cast(uint2_, pv);
                W[qt][ts][0] = u.x;
                W[qt][ts][1] = u.y;
            }
            rs += __shfl_xor(rs, 16);
            rs += __shfl_xor(rs, 32);
            li[qt] = li[qt] * alpha + rs;
#pragma unroll
            for (int ht = 0; ht < 8; ht++) ot[qt][ht] *= alpha;
        }

#pragma unroll
        for (int ck = 0; ck < 2; ck++) {
            bf16x8 pf[2];
#pragma unroll
            for (int qt = 0; qt < 2; qt++) {
                const unsigned a0 = W[qt][2 * ck][0], a1 = W[qt][2 * ck][1];
                const unsigned b0 = W[qt][2 * ck + 1][0], b1 = W[qt][2 * ck + 1][1];
                unsigned pw0, pw1, pw2, pw3;
                { const unsigned xa = __shfl((int)a0, s0), xb = __shfl((int)b0, s0); pw0 = hi ? xb : xa; }
                { const unsigned xa = __shfl((int)a1, s0), xb = __shfl((int)b1, s0); pw1 = hi ? xb : xa; }
                { const unsigned xa = __shfl((int)a0, s1), xb = __shfl((int)b0, s1); pw2 = hi ? xb : xa; }
                { const unsigned xa = __shfl((int)a1, s1), xb = __shfl((int)b1, s1); pw3 = hi ? xb : xa; }
                uint4_ pv4 = {pw0, pw1, pw2, pw3};
                pf[qt] = __builtin_bit_cast(bf16x8, pv4);
            }
#pragma unroll
            for (int ht = 0; ht < 8; ht++) {
                bf16x8 vf = *(const bf16x8*)(Vs + (16 * ht + m16) * 64 +
                                             ((((ck << 2) + quad) ^ (m16 & 7)) << 3));
                ot[0][ht] = MFMA_BF16(vf, pf[0], ot[0][ht]);
                ot[1][ht] = MFMA_BF16(vf, pf[1], ot[1][ht]);
            }
        }
    }

#pragma unroll
    for (int qt = 0; qt < 2; qt++) {
        if (quad == 0) {
            const int row = w * 32 + qt * 16 + m16;
            ml[pidx * 256 + row] = mi[qt];
            ml[pidx * 256 + 128 + row] = li[qt];
        }
    }

    __syncthreads();
    const float inv0 = 1.f / li[0], inv1 = 1.f / li[1];
    bf16_t* Oq = smem + w * (32 * 128);
#pragma unroll
    for (int qt = 0; qt < 2; qt++) {
        const float inv = qt ? inv1 : inv0;
        const int r = qt * 16 + m16;
#pragma unroll
        for (int ht = 0; ht < 8; ht++) {
            bf16x4 v = {(bf16_t)(ot[qt][ht][0] * inv), (bf16_t)(ot[qt][ht][1] * inv),
                        (bf16_t)(ot[qt][ht][2] * inv), (bf16_t)(ot[qt][ht][3] * inv)};
            const int chunk = (2 * ht + (quad >> 1)) ^ (r & 7);
            *(bf16x4*)((char*)Oq + r * 256 + (chunk << 4) + ((quad & 1) << 3)) = v;
        }
    }
    __syncthreads();
    {
        const int qrow = l >> 1, hf = l & 1;
        const int qloc = w * 32 + qrow;
        bf16_t* dst = Opart + (pidx * 128 + qloc) * 128 + hf * 64;
#pragma unroll
        for (int j = 0; j < 8; j++) {
            const bf16x8 o = *(const bf16x8*)((char*)Oq + qrow * 256 +
                                              ((((hf << 3) + j) ^ (qrow & 7)) << 4));
            *(bf16x8*)(dst + j * 8) = o;
        }
    }
}

// ---------------------------------------------------------------------------
// Combine partial attention chunks: ctx[t][n*H+h] = sum_c w_c * O_c
// ---------------------------------------------------------------------------
__global__ __launch_bounds__(256) void combine_kernel(const bf16_t* __restrict__ Opart,
                                                      const float* __restrict__ ml,
                                                      bf16_t* __restrict__ ctx) {
    const int qb = blockIdx.x, n = blockIdx.y;
    const int C = (qb + 4) >> 2;
    int f0 = 0;
    for (int i = 0; i < qb; i++) f0 += (i + 4) >> 2;
    const int tid = threadIdx.x;
    const int qrow = tid >> 1, half = tid & 1;
    const long pb = (long)n * FPH_ + f0;

    float m[4], lv[4], wv[4];
    float M = -1e30f;
    for (int c = 0; c < C; c++) {
        m[c] = ml[(pb + c) * 256 + qrow];
        lv[c] = ml[(pb + c) * 256 + 128 + qrow];
        M = fmaxf(M, m[c]);
    }
    float wsum = 0.f;
    for (int c = 0; c < C; c++) { wv[c] = lv[c] * __expf(m[c] - M); wsum += wv[c]; }
    const float invw = 1.f / wsum;
    for (int c = 0; c < C; c++) wv[c] *= invw;

    bf16_t* dst = ctx + ((long)(qb * 128 + qrow)) * (NH_ * H_) + n * H_ + half * 64;
#pragma unroll
    for (int j = 0; j < 8; j++) {
        float acc[8] = {0, 0, 0, 0, 0, 0, 0, 0};
        for (int c = 0; c < C; c++) {
            bf16x8 v = *(const bf16x8*)(Opart + ((pb + c) * 128 + qrow) * 128 + half * 64 + j * 8);
#pragma unroll
            for (int e = 0; e < 8; e++) acc[e] += wv[c] * (float)v[e];
        }
        bf16x8 o;
#pragma unroll
        for (int e = 0; e < 8; e++) o[e] = (bf16_t)acc[e];
        *(bf16x8*)(dst + j * 8) = o;
    }
}

// ---------------------------------------------------------------------------
extern "C" void kernel_launch(void* const* d_in, const int* in_sizes, int n_in,
                              void* d_out, int out_size, void* d_ws, size_t ws_size,
                              hipStream_t stream) {
    const float* x  = (const float*)d_in[0];
    const int*   ps = (const int*)d_in[1];
    const float* wq = (const float*)d_in[2];
    const float* bq = (const float*)d_in[3];
    const float* wk = (const float*)d_in[4];
    const float* bk = (const float*)d_in[5];
    const float* wv = (const float*)d_in[6];
    const float* bv = (const float*)d_in[7];
    const float* wo = (const float*)d_in[8];
    float* out = (float*)d_out;

    bf16_t* xb  = (bf16_t*)d_ws;                 // [2048][3584]    x in bf16
    bf16_t* wt  = xb + (long)T_ * D_;            // [36][128][3584] transposed qkv weights
    bf16_t* woT = wt + (long)NW_ * H_ * D_;      // [3584][3584]    woT[d][n*H+h]
    bf16_t* qkv = woT + (long)D_ * D_;           // [36][2048][128] projections
    bf16_t* vT  = qkv + (long)NW_ * T_ * H_;     // [4][128][2048]  V transposed
    bf16_t* ctx = vT + (long)KV_ * H_ * T_;      // [2048][3584]    attention output (bf16)
    // partials alias xb+wt (dead after gemm_qkv): 36.7 MB + 1.15 MB < 47.7 MB
    bf16_t* Opart = (bf16_t*)d_ws;               // [28*40][128][128] bf16
    float*  ml    = (float*)((char*)d_ws + (long)NH_ * FPH_ * 128 * 128 * 2);  // [28*40][2][128]

    const long whd = (long)D_ * H_;
    convert_f32_bf16<<<((long)T_ * D_ / 8 + 255) / 256, 256, 0, stream>>>(x, xb);
    transpose64_f32_bf16<<<dim3(H_ / 64, D_ / 64, NH_), 256, 0, stream>>>(wq, wt, D_, H_, whd, whd);
    transpose64_f32_bf16<<<dim3(H_ / 64, D_ / 64, KV_), 256, 0, stream>>>(wk, wt + (long)NH_ * whd, D_, H_, whd, whd);
    transpose64_f32_bf16<<<dim3(H_ / 64, D_ / 64, KV_), 256, 0, stream>>>(wv, wt + (long)(NH_ + KV_) * whd, D_, H_, whd, whd);
    transpose64_f32_bf16<<<dim3(D_ / 64, D_ / 64, 1), 256, 0, stream>>>(wo, woT, D_, D_, 0, 0);

    gemm128_kernel<true><<<dim3(T_ / 128 * NW_), 256, 0, stream>>>(xb, wt, bq, bk, bv, qkv, nullptr, NW_);
    rope_kernel<<<(32 * T_ * 64) / 256, 256, 0, stream>>>(qkv, ps);
    transpose32_bf16<<<dim3(H_ / 32, T_ / 32, KV_), 256, 0, stream>>>(qkv + (long)(NH_ + KV_) * T_ * H_, vT,
                                                                      T_, H_, (long)T_ * H_, (long)T_ * H_);
    attn_kernel<<<dim3(FPH_, NH_), 256, 0, stream>>>(qkv, vT, Opart, ml);
    combine_kernel<<<dim3(T_ / 128, NH_), 256, 0, stream>>>(Opart, ml, ctx);
    gemm128_kernel<false><<<dim3(T_ / 128 * (D_ / 128)), 256, 0, stream>>>(ctx, woT, nullptr, nullptr, nullptr,
                                                                           nullptr, out, D_ / 128);
}

// Round 8
// 473.495 us; speedup vs baseline: 1.2794x; 1.1155x over previous
//
#include <hip/hip_runtime.h>

#define AS1 __attribute__((address_space(1)))
#define AS3 __attribute__((address_space(3)))

typedef __bf16 bf16_t;
typedef __bf16 bf16x8 __attribute__((ext_vector_type(8)));
typedef __bf16 bf16x4 __attribute__((ext_vector_type(4)));
typedef float  floatx4 __attribute__((ext_vector_type(4)));
typedef unsigned int uint2_ __attribute__((ext_vector_type(2)));
typedef unsigned int uint4_ __attribute__((ext_vector_type(4)));

#define MFMA_BF16(a, b, c) __builtin_amdgcn_mfma_f32_16x16x32_bf16(a, b, c, 0, 0, 0)

static constexpr int T_  = 2048;
static constexpr int D_  = 3584;
static constexpr int NH_ = 28;   // query heads
static constexpr int KV_ = 4;    // kv heads
static constexpr int H_  = 128;  // head dim
static constexpr int NW_ = 36;   // 28 q + 4 k + 4 v projection heads

// H^-0.5 * log2(e): softmax runs in the exp2 domain (R2/R3-verified numerics)
#define QSCALE 0.12754245778287616f

#define WAITV(n) asm volatile("s_waitcnt vmcnt(" #n ")" ::: "memory")

// ---------------------------------------------------------------------------
// Elementwise fp32 -> bf16 convert (8 elems/thread)
// ---------------------------------------------------------------------------
__global__ void convert_f32_bf16(const float* __restrict__ src, bf16_t* __restrict__ dst) {
    const long i = (long)(blockIdx.x * blockDim.x + threadIdx.x) * 8;
    float4 a = ((const float4*)(src + i))[0];
    float4 b = ((const float4*)(src + i))[1];
    bf16x8 o = {(bf16_t)a.x, (bf16_t)a.y, (bf16_t)a.z, (bf16_t)a.w,
                (bf16_t)b.x, (bf16_t)b.y, (bf16_t)b.z, (bf16_t)b.w};
    *(bf16x8*)(dst + i) = o;
}

// ---------------------------------------------------------------------------
// 64x64-tile fp32 -> bf16 transpose, vectorized: dst[c][r] = (bf16)src[r][c]
// ---------------------------------------------------------------------------
__global__ __launch_bounds__(256) void transpose64_f32_bf16(const float* __restrict__ src,
                                                            bf16_t* __restrict__ dst,
                                                            int R, int C, long sStride, long dStride) {
    __shared__ bf16_t t[64][68];
    src += (long)blockIdx.z * sStride;
    dst += (long)blockIdx.z * dStride;
    const int tid = threadIdx.x;
    const int r0 = blockIdx.y * 64, c0 = blockIdx.x * 64;
#pragma unroll
    for (int p = 0; p < 4; p++) {
        const int row = (tid >> 4) + p * 16, col4 = tid & 15;
        float4 v = *(const float4*)(src + (long)(r0 + row) * C + c0 + col4 * 4);
        bf16x4 b = {(bf16_t)v.x, (bf16_t)v.y, (bf16_t)v.z, (bf16_t)v.w};
        *(bf16x4*)&t[row][col4 * 4] = b;
    }
    __syncthreads();
#pragma unroll
    for (int p = 0; p < 2; p++) {
        const int cc = (tid >> 3) + p * 32, k = tid & 7;
        bf16x8 o;
#pragma unroll
        for (int j = 0; j < 8; j++) o[j] = t[8 * k + j][cc];
        *(bf16x8*)(dst + (long)(c0 + cc) * R + r0 + 8 * k) = o;
    }
}

// ---------------------------------------------------------------------------
// Small 32x32 bf16 transpose (used for V^T only, 2 MB)
// ---------------------------------------------------------------------------
__global__ void transpose32_bf16(const bf16_t* __restrict__ src, bf16_t* __restrict__ dst,
                                 int R, int C, long sStride, long dStride) {
    __shared__ bf16_t tile[32][33];
    src += (long)blockIdx.z * sStride;
    dst += (long)blockIdx.z * dStride;
    const int tx = threadIdx.x & 31, ty = threadIdx.x >> 5;
    const int r0 = blockIdx.y * 32, c0 = blockIdx.x * 32;
#pragma unroll
    for (int i = 0; i < 4; i++) {
        int rr = ty + i * 8;
        tile[rr][tx] = src[(long)(r0 + rr) * C + c0 + tx];
    }
    __syncthreads();
#pragma unroll
    for (int i = 0; i < 4; i++) {
        int cc = ty + i * 8;
        dst[(long)(c0 + cc) * R + r0 + tx] = tile[tx][cc];
    }
}

// ---------------------------------------------------------------------------
// R9 GEMM (R7-verified): BM=BN=128, BK=32, 4 waves, ring-3 LDS, counted
// WAITV(4) + raw s_barrier, pair-XOR swizzle, s_setprio. Unchanged.
// ---------------------------------------------------------------------------
__device__ __forceinline__ void stage_t128(const bf16_t* __restrict__ g, int kt,
                                           bf16_t* sl, int tid) {
#pragma unroll
    for (int c = 0; c < 2; c++) {
        const int chunk = c * 256 + tid;      // 512 chunks: 128 rows x 4
        const int pair = chunk >> 3, P = chunk & 7;
        const int L = P ^ (pair & 7);
        const int row = (pair << 1) | (L >> 2);
        const int cc = L & 3;
        __builtin_amdgcn_global_load_lds((const AS1 void*)(g + (long)row * D_ + kt + cc * 8),
                                         (AS3 void*)(sl + chunk * 8), 16, 0, 0);
    }
}

__device__ __forceinline__ void gstep(const bf16_t* __restrict__ As, const bf16_t* __restrict__ Bs,
                                      bf16_t* Asn, bf16_t* Bsn,
                                      const bf16_t* __restrict__ Ag, const bf16_t* __restrict__ Bg,
                                      int ktn, bool do_stage, int tid,
                                      int wr, int wn, int m16, int quad,
                                      floatx4 acc[4][4]) {
    bf16x8 af[4], bfv[4];
#pragma unroll
    for (int i = 0; i < 4; i++) {
        const int rr = wr * 64 + i * 16 + m16;
        const int L = ((rr & 1) << 2) | quad;
        af[i] = *(const bf16x8*)(As + ((rr >> 1) << 6) + ((L ^ ((rr >> 1) & 7)) << 3));
    }
#pragma unroll
    for (int j = 0; j < 4; j++) {
        const int rr = wn * 64 + j * 16 + m16;
        const int L = ((rr & 1) << 2) | quad;
        bfv[j] = *(const bf16x8*)(Bs + ((rr >> 1) << 6) + ((L ^ ((rr >> 1) & 7)) << 3));
    }
    if (do_stage) {
        stage_t128(Ag, ktn, Asn, tid);
        stage_t128(Bg, ktn, Bsn, tid);
    }
    __builtin_amdgcn_s_setprio(1);
#pragma unroll
    for (int i = 0; i < 4; i++)
#pragma unroll
        for (int j = 0; j < 4; j++) acc[i][j] = MFMA_BF16(af[i], bfv[j], acc[i][j]);
    __builtin_amdgcn_s_setprio(0);
}

#define GSTEP(AS_, BS_, ASN_, BSN_, STG_)                                         \
    WAITV(4); __builtin_amdgcn_s_barrier();                                       \
    gstep(AS_, BS_, ASN_, BSN_, Ag, Bg, kts, STG_, tid, wr, wn, m16, quad, acc);  \
    kts += 32;

template<bool QKV>
__global__ __launch_bounds__(256, 3) void gemm128_kernel(const bf16_t* __restrict__ A,
                                                         const bf16_t* __restrict__ Bt,
                                                         const float* __restrict__ bq,
                                                         const float* __restrict__ bk,
                                                         const float* __restrict__ bv,
                                                         bf16_t* __restrict__ outb,
                                                         float* __restrict__ outf,
                                                         int NT) {
    __shared__ bf16_t As0[128 * 32], As1[128 * 32], As2[128 * 32];
    __shared__ bf16_t Bs0[128 * 32], Bs1[128 * 32], Bs2[128 * 32];

    const int nwg = gridDim.x;
    const int lin = blockIdx.x;
    const int wg = (lin & 7) * (nwg >> 3) + (lin >> 3);   // XCD-chunked (nwg%8==0)
    const int mt = wg / NT, nt = wg % NT;

    const bf16_t* Ag = A + (long)mt * 128 * D_;
    const bf16_t* Bg = Bt + (long)nt * 128 * D_;

    const int tid = threadIdx.x, w = tid >> 6, l = tid & 63;
    const int m16 = l & 15, quad = l >> 4;
    const int wr = w >> 1, wn = w & 1;

    floatx4 acc[4][4];
#pragma unroll
    for (int i = 0; i < 4; i++)
#pragma unroll
        for (int j = 0; j < 4; j++) acc[i][j] = (floatx4){0.f, 0.f, 0.f, 0.f};

    stage_t128(Ag, 0, As0, tid);  stage_t128(Bg, 0, Bs0, tid);
    stage_t128(Ag, 32, As1, tid); stage_t128(Bg, 32, Bs1, tid);
    int kts = 64;

#pragma unroll 1
    for (int g = 0; g < 36; g++) {                 // s = 0..107
        GSTEP(As0, Bs0, As2, Bs2, true)
        GSTEP(As1, Bs1, As0, Bs0, true)
        GSTEP(As2, Bs2, As1, Bs1, true)
    }
    GSTEP(As0, Bs0, As2, Bs2, true)                // s=108
    GSTEP(As1, Bs1, As0, Bs0, true)                // s=109
    WAITV(4); __builtin_amdgcn_s_barrier();
    gstep(As2, Bs2, As0, Bs0, Ag, Bg, 0, false, tid, wr, wn, m16, quad, acc);   // s=110
    WAITV(0); __builtin_amdgcn_s_barrier();
    gstep(As0, Bs0, As1, Bs1, Ag, Bg, 0, false, tid, wr, wn, m16, quad, acc);   // s=111

    if (QKV) {
        const int hd = nt;
        const float* bias = hd < NH_ ? bq + hd * H_
                                     : (hd < NH_ + KV_ ? bk + (hd - NH_) * H_
                                                       : bv + (hd - NH_ - KV_) * H_);
        bf16_t* C = outb + (long)hd * T_ * H_ + (long)(mt * 128) * H_;
#pragma unroll
        for (int j = 0; j < 4; j++) {
            const int col = wn * 64 + j * 16 + m16;
            const float bb = bias[col];
#pragma unroll
            for (int i = 0; i < 4; i++) {
                const int row = wr * 64 + i * 16 + quad * 4;
#pragma unroll
                for (int r = 0; r < 4; r++) C[(long)(row + r) * H_ + col] = (bf16_t)(acc[i][j][r] + bb);
            }
        }
    } else {
        float* C = outf + (long)(mt * 128) * D_ + nt * 128;
#pragma unroll
        for (int j = 0; j < 4; j++) {
            const int col = wn * 64 + j * 16 + m16;
#pragma unroll
            for (int i = 0; i < 4; i++) {
                const int row = wr * 64 + i * 16 + quad * 4;
#pragma unroll
                for (int r = 0; r < 4; r++) C[(long)(row + r) * D_ + col] = acc[i][j][r];
            }
        }
    }
}

// ---------------------------------------------------------------------------
// In-place RoPE; q heads scaled by H^-0.5 * log2e (exp2-domain softmax)
// ---------------------------------------------------------------------------
__global__ void rope_kernel(bf16_t* __restrict__ qkv, const int* __restrict__ pos) {
    const int idx = blockIdx.x * blockDim.x + threadIdx.x;
    const int h = idx & 63;
    const int t = (idx >> 6) & (T_ - 1);
    const int hd = idx >> 17;
    if (hd >= NH_ + KV_) return;
    bf16_t* p = qkv + ((long)hd * T_ + t) * H_;
    const float x1 = (float)p[h], x2 = (float)p[h + 64];
    const float inv = expf(-(float)h * (13.815510557964274f / 64.f));
    const float ang = (float)pos[t] * inv;
    float s, c;
    sincosf(ang, &s, &c);
    float o1 = x1 * c - x2 * s;
    float o2 = x2 * c + x1 * s;
    if (hd < NH_) { o1 *= QSCALE; o2 *= QSCALE; }
    p[h] = (bf16_t)o1;
    p[h + 64] = (bf16_t)o2;
}

// ---------------------------------------------------------------------------
// R8 flash attention: one block per (256-row q-tile, head) = 224 blocks,
// every block on its own CU from t=0 (no generations, no churn, no split-s).
// 8 waves/block: wave w owns rows qt*256+w*32..+31, K/V staged cooperatively
// (2x amortization vs 4-wave split-s), double-buffered with stage-ahead-1
// (R2-verified static-identity pipeline). Per-wave causal compute-skip keeps
// barrier counts block-uniform. No Opart/ml/combine: O normalized in-wave and
// written straight to ctx (R3-verified epilogue + exp2 + defer-max).
// ---------------------------------------------------------------------------
__device__ __forceinline__ void attn_stage8(const bf16_t* __restrict__ Kg,
                                            const bf16_t* __restrict__ Vg,
                                            int sb, int tid,
                                            const int kOff[2], const int vOff[2],
                                            bf16_t* Ks, bf16_t* Vs) {
    const long kBase = (long)sb * 64 * H_;
    const int  vBase = sb * 64;
#pragma unroll
    for (int i = 0; i < 2; i++)
        __builtin_amdgcn_global_load_lds((const AS1 void*)(Kg + kBase + kOff[i]),
                                         (AS3 void*)(Ks + (i * 512 + tid) * 8), 16, 0, 0);
#pragma unroll
    for (int i = 0; i < 2; i++)
        __builtin_amdgcn_global_load_lds((const AS1 void*)(Vg + vBase + vOff[i]),
                                         (AS3 void*)(Vs + (i * 512 + tid) * 8), 16, 0, 0);
}

__device__ __forceinline__ void attn_step8(const bf16_t* __restrict__ Ks,
                                           const bf16_t* __restrict__ Vs,
                                           int sb, int q0, int m16, int quad,
                                           int s0, int s1, bool hiq,
                                           const bf16x8 qf[2][4], floatx4 ot[2][8],
                                           float mi[2], float li[2]) {
    floatx4 stv[2][4];
    __builtin_amdgcn_s_setprio(1);
#pragma unroll
    for (int ts = 0; ts < 4; ts++) {
        bf16x8 kf[4];
#pragma unroll
        for (int kk = 0; kk < 4; kk++)
            kf[kk] = *(const bf16x8*)(Ks + (16 * ts + m16) * 128 +
                                      ((((kk << 2) + quad) ^ (m16 & 7)) << 3));
#pragma unroll
        for (int qt = 0; qt < 2; qt++) {
            floatx4 c = (floatx4){0.f, 0.f, 0.f, 0.f};
#pragma unroll
            for (int kk = 0; kk < 4; kk++) c = MFMA_BF16(kf[kk], qf[qt][kk], c);
            stv[qt][ts] = c;
        }
    }
    __builtin_amdgcn_s_setprio(0);

    unsigned int W[2][4][2];
    const bool need_mask = (sb * 64 + 63) > q0;
#pragma unroll
    for (int qt = 0; qt < 2; qt++) {
        const int qg = q0 + qt * 16 + m16;
        if (need_mask) {
#pragma unroll
            for (int ts = 0; ts < 4; ts++)
#pragma unroll
                for (int r = 0; r < 4; r++) {
                    const int sg = sb * 64 + ts * 16 + quad * 4 + r;
                    if (sg > qg) stv[qt][ts][r] = -1e30f;
                }
        }
        float mx = -1e30f;
#pragma unroll
        for (int ts = 0; ts < 4; ts++)
#pragma unroll
            for (int r = 0; r < 4; r++) mx = fmaxf(mx, stv[qt][ts][r]);
        mx = fmaxf(mx, __shfl_xor(mx, 16));
        mx = fmaxf(mx, __shfl_xor(mx, 32));
        float mn = mi[qt];
        if (__any(mx > mi[qt] + 8.f)) {          // defer-max (T13, R3-verified)
            mn = fmaxf(mi[qt], mx);
            const float alpha = exp2f(mi[qt] - mn);
            mi[qt] = mn;
            li[qt] *= alpha;
#pragma unroll
            for (int ht = 0; ht < 8; ht++) ot[qt][ht] *= alpha;
        }
        float rs = 0.f;
#pragma unroll
        for (int ts = 0; ts < 4; ts++) {
            const float p0 = exp2f(stv[qt][ts][0] - mn);
            const float p1 = exp2f(stv[qt][ts][1] - mn);
            const float p2 = exp2f(stv[qt][ts][2] - mn);
            const float p3 = exp2f(stv[qt][ts][3] - mn);
            rs += p0 + p1 + p2 + p3;
            bf16x4 pv = {(bf16_t)p0, (bf16_t)p1, (bf16_t)p2, (bf16_t)p3};
            uint2_ u = __builtin_bit_cast(uint2_, pv);
            W[qt][ts][0] = u.x;
            W[qt][ts][1] = u.y;
        }
        rs += __shfl_xor(rs, 16);
        rs += __shfl_xor(rs, 32);
        li[qt] += rs;
    }

#pragma unroll
    for (int ck = 0; ck < 2; ck++) {
        bf16x8 pf[2];
#pragma unroll
        for (int qt = 0; qt < 2; qt++) {
            const unsigned a0 = W[qt][2 * ck][0], a1 = W[qt][2 * ck][1];
            const unsigned b0 = W[qt][2 * ck + 1][0], b1 = W[qt][2 * ck + 1][1];
            unsigned pw0, pw1, pw2, pw3;
            { const unsigned xa = __shfl((int)a0, s0), xb = __shfl((int)b0, s0); pw0 = hiq ? xb : xa; }
            { const unsigned xa = __shfl((int)a1, s0), xb = __shfl((int)b1, s0); pw1 = hiq ? xb : xa; }
            { const unsigned xa = __shfl((int)a0, s1), xb = __shfl((int)b0, s1); pw2 = hiq ? xb : xa; }
            { const unsigned xa = __shfl((int)a1, s1), xb = __shfl((int)b1, s1); pw3 = hiq ? xb : xa; }
            uint4_ pv4 = {pw0, pw1, pw2, pw3};
            pf[qt] = __builtin_bit_cast(bf16x8, pv4);
        }
        __builtin_amdgcn_s_setprio(1);
#pragma unroll
        for (int ht = 0; ht < 8; ht++) {
            bf16x8 vf = *(const bf16x8*)(Vs + (16 * ht + m16) * 64 +
                                         ((((ck << 2) + quad) ^ (m16 & 7)) << 3));
            ot[0][ht] = MFMA_BF16(vf, pf[0], ot[0][ht]);
            ot[1][ht] = MFMA_BF16(vf, pf[1], ot[1][ht]);
        }
        __builtin_amdgcn_s_setprio(0);
    }
}

__global__ __launch_bounds__(512) void attn_kernel(const bf16_t* __restrict__ qkv,
                                                   const bf16_t* __restrict__ vT,
                                                   bf16_t* __restrict__ ctx) {
    __shared__ bf16_t smem[32768];               // [K0 8K][K1 8K][V0 8K][V1 8K] elems = 64 KB
    bf16_t* K0 = smem;
    bf16_t* K1 = smem + 8192;
    bf16_t* V0 = smem + 16384;
    bf16_t* V1 = smem + 24576;

    const int qt = blockIdx.x, n = blockIdx.y;
    const int kvh = n / 7;
    const bf16_t* Q  = qkv + (long)n * T_ * H_;
    const bf16_t* Kg = qkv + (long)(NH_ + kvh) * T_ * H_;
    const bf16_t* Vg = vT + (long)kvh * H_ * T_;   // [h][t]

    const int tid = threadIdx.x, w = tid >> 6, l = tid & 63;
    const int m16 = l & 15, quad = l >> 4;
    const int q0 = qt * 256 + w * 32;

    // Pre-swizzled global source offsets; LDS dest linear (chunk*16B).
    int kOff[2], vOff[2];
#pragma unroll
    for (int i = 0; i < 2; i++) {
        const int ck_ = i * 512 + tid;           // K: 64 rows x 16 chunks = 1024
        const int kr = ck_ >> 4, kc = ck_ & 15;
        kOff[i] = kr * H_ + ((kc ^ (kr & 7)) << 3);
        const int vr = ck_ >> 3, vc = ck_ & 7;   // V: 128 rows x 8 chunks = 1024
        vOff[i] = vr * T_ + ((vc ^ (vr & 7)) << 3);
    }

    bf16x8 qf[2][4];
#pragma unroll
    for (int qt2 = 0; qt2 < 2; qt2++)
#pragma unroll
        for (int kk = 0; kk < 4; kk++)
            qf[qt2][kk] = *(const bf16x8*)(Q + (long)(q0 + qt2 * 16 + m16) * H_ + kk * 32 + quad * 8);

    floatx4 ot[2][8];
#pragma unroll
    for (int qt2 = 0; qt2 < 2; qt2++)
#pragma unroll
        for (int ht = 0; ht < 8; ht++) ot[qt2][ht] = (floatx4){0.f, 0.f, 0.f, 0.f};
    float mi[2] = {-1e30f, -1e30f}, li[2] = {0.f, 0.f};

    const int s0 = m16 + ((quad & 1) << 5);
    const int s1 = s0 + 16;
    const bool hiq = (quad & 2) != 0;

    const int E = 4 * (qt + 1);                  // block-uniform trip count
    const int sbEw = (q0 + 95) >> 6;             // this wave's causal end

    attn_stage8(Kg, Vg, 0, tid, kOff, vOff, K0, V0);
    int sb = 0;
    while (true) {
        __syncthreads();                         // drains stage(sb) DMA; orders buf reuse
        if (sb + 1 < E) attn_stage8(Kg, Vg, sb + 1, tid, kOff, vOff, K1, V1);
        if (sb < sbEw) attn_step8(K0, V0, sb, q0, m16, quad, s0, s1, hiq, qf, ot, mi, li);
        if (++sb >= E) break;
        __syncthreads();
        if (sb + 1 < E) attn_stage8(Kg, Vg, sb + 1, tid, kOff, vOff, K0, V0);
        if (sb < sbEw) attn_step8(K1, V1, sb, q0, m16, quad, s0, s1, hiq, qf, ot, mi, li);
        if (++sb >= E) break;
    }
    __syncthreads();                             // all waves done before smem reuse

    // Epilogue: normalize, per-wave swizzled transpose (8 KB slice), direct ctx write
    const float inv0 = 1.f / li[0], inv1 = 1.f / li[1];
    bf16_t* Oq = smem + w * 4096;
#pragma unroll
    for (int qt2 = 0; qt2 < 2; qt2++) {
        const float inv = qt2 ? inv1 : inv0;
        const int r = qt2 * 16 + m16;
#pragma unroll
        for (int ht = 0; ht < 8; ht++) {
            bf16x4 v = {(bf16_t)(ot[qt2][ht][0] * inv), (bf16_t)(ot[qt2][ht][1] * inv),
                        (bf16_t)(ot[qt2][ht][2] * inv), (bf16_t)(ot[qt2][ht][3] * inv)};
            const int chunk = (2 * ht + (quad >> 1)) ^ (r & 7);
            *(bf16x4*)((char*)Oq + r * 256 + (chunk << 4) + ((quad & 1) << 3)) = v;
        }
    }
    {
        const int qrow = l >> 1, hf = l & 1;
        bf16_t* dst = ctx + (long)(q0 + qrow) * (NH_ * H_) + n * H_ + hf * 64;
#pragma unroll
        for (int j = 0; j < 8; j++) {
            const bf16x8 o = *(const bf16x8*)((char*)Oq + qrow * 256 +
                                              ((((hf << 3) + j) ^ (qrow & 7)) << 4));
            *(bf16x8*)(dst + j * 8) = o;
        }
    }
}

// ---------------------------------------------------------------------------
extern "C" void kernel_launch(void* const* d_in, const int* in_sizes, int n_in,
                              void* d_out, int out_size, void* d_ws, size_t ws_size,
                              hipStream_t stream) {
    const float* x  = (const float*)d_in[0];
    const int*   ps = (const int*)d_in[1];
    const float* wq = (const float*)d_in[2];
    const float* bq = (const float*)d_in[3];
    const float* wk = (const float*)d_in[4];
    const float* bk = (const float*)d_in[5];
    const float* wv = (const float*)d_in[6];
    const float* bv = (const float*)d_in[7];
    const float* wo = (const float*)d_in[8];
    float* out = (float*)d_out;

    bf16_t* xb  = (bf16_t*)d_ws;                 // [2048][3584]    x in bf16
    bf16_t* wt  = xb + (long)T_ * D_;            // [36][128][3584] transposed qkv weights
    bf16_t* woT = wt + (long)NW_ * H_ * D_;      // [3584][3584]    woT[d][n*H+h]
    bf16_t* qkv = woT + (long)D_ * D_;           // [36][2048][128] projections
    bf16_t* vT  = qkv + (long)NW_ * T_ * H_;     // [4][128][2048]  V transposed
    bf16_t* ctx = vT + (long)KV_ * H_ * T_;      // [2048][3584]    attention output (bf16)

    const long whd = (long)D_ * H_;
    convert_f32_bf16<<<((long)T_ * D_ / 8 + 255) / 256, 256, 0, stream>>>(x, xb);
    transpose64_f32_bf16<<<dim3(H_ / 64, D_ / 64, NH_), 256, 0, stream>>>(wq, wt, D_, H_, whd, whd);
    transpose64_f32_bf16<<<dim3(H_ / 64, D_ / 64, KV_), 256, 0, stream>>>(wk, wt + (long)NH_ * whd, D_, H_, whd, whd);
    transpose64_f32_bf16<<<dim3(H_ / 64, D_ / 64, KV_), 256, 0, stream>>>(wv, wt + (long)(NH_ + KV_) * whd, D_, H_, whd, whd);
    transpose64_f32_bf16<<<dim3(D_ / 64, D_ / 64, 1), 256, 0, stream>>>(wo, woT, D_, D_, 0, 0);

    gemm128_kernel<true><<<dim3(T_ / 128 * NW_), 256, 0, stream>>>(xb, wt, bq, bk, bv, qkv, nullptr, NW_);
    rope_kernel<<<(32 * T_ * 64) / 256, 256, 0, stream>>>(qkv, ps);
    transpose32_bf16<<<dim3(H_ / 32, T_ / 32, KV_), 256, 0, stream>>>(qkv + (long)(NH_ + KV_) * T_ * H_, vT,
                                                                      T_, H_, (long)T_ * H_, (long)T_ * H_);
    attn_kernel<<<dim3(T_ / 256, NH_), 512, 0, stream>>>(qkv, vT, ctx);
    gemm128_kernel<false><<<dim3(T_ / 128 * (D_ / 128)), 256, 0, stream>>>(ctx, woT, nullptr, nullptr, nullptr,
                                                                           nullptr, out, D_ / 128);
}

// Round 9
// 450.872 us; speedup vs baseline: 1.3436x; 1.0502x over previous
//
#include <hip/hip_runtime.h>

#define AS1 __attribute__((address_space(1)))
#define AS3 __attribute__((address_space(3)))

typedef __bf16 bf16_t;
typedef __bf16 bf16x8 __attribute__((ext_vector_type(8)));
typedef __bf16 bf16x4 __attribute__((ext_vector_type(4)));
typedef float  floatx4 __attribute__((ext_vector_type(4)));
typedef unsigned int uint2_ __attribute__((ext_vector_type(2)));
typedef unsigned int uint4_ __attribute__((ext_vector_type(4)));

#define MFMA_BF16(a, b, c) __builtin_amdgcn_mfma_f32_16x16x32_bf16(a, b, c, 0, 0, 0)

static constexpr int T_  = 2048;
static constexpr int D_  = 3584;
static constexpr int NH_ = 28;   // query heads
static constexpr int KV_ = 4;    // kv heads
static constexpr int H_  = 128;  // head dim
static constexpr int NW_ = 36;   // 28 q + 4 k + 4 v projection heads

// H^-0.5 * log2(e): softmax runs in the exp2 domain (R2/R3-verified numerics)
#define QSCALE 0.12754245778287616f

#define WAITV(n) asm volatile("s_waitcnt vmcnt(" #n ")" ::: "memory")

// ---------------------------------------------------------------------------
// Elementwise fp32 -> bf16 convert (8 elems/thread)
// ---------------------------------------------------------------------------
__global__ void convert_f32_bf16(const float* __restrict__ src, bf16_t* __restrict__ dst) {
    const long i = (long)(blockIdx.x * blockDim.x + threadIdx.x) * 8;
    float4 a = ((const float4*)(src + i))[0];
    float4 b = ((const float4*)(src + i))[1];
    bf16x8 o = {(bf16_t)a.x, (bf16_t)a.y, (bf16_t)a.z, (bf16_t)a.w,
                (bf16_t)b.x, (bf16_t)b.y, (bf16_t)b.z, (bf16_t)b.w};
    *(bf16x8*)(dst + i) = o;
}

// ---------------------------------------------------------------------------
// 64x64-tile fp32 -> bf16 transpose, vectorized: dst[c][r] = (bf16)src[r][c]
// ---------------------------------------------------------------------------
__global__ __launch_bounds__(256) void transpose64_f32_bf16(const float* __restrict__ src,
                                                            bf16_t* __restrict__ dst,
                                                            int R, int C, long sStride, long dStride) {
    __shared__ bf16_t t[64][68];
    src += (long)blockIdx.z * sStride;
    dst += (long)blockIdx.z * dStride;
    const int tid = threadIdx.x;
    const int r0 = blockIdx.y * 64, c0 = blockIdx.x * 64;
#pragma unroll
    for (int p = 0; p < 4; p++) {
        const int row = (tid >> 4) + p * 16, col4 = tid & 15;
        float4 v = *(const float4*)(src + (long)(r0 + row) * C + c0 + col4 * 4);
        bf16x4 b = {(bf16_t)v.x, (bf16_t)v.y, (bf16_t)v.z, (bf16_t)v.w};
        *(bf16x4*)&t[row][col4 * 4] = b;
    }
    __syncthreads();
#pragma unroll
    for (int p = 0; p < 2; p++) {
        const int cc = (tid >> 3) + p * 32, k = tid & 7;
        bf16x8 o;
#pragma unroll
        for (int j = 0; j < 8; j++) o[j] = t[8 * k + j][cc];
        *(bf16x8*)(dst + (long)(c0 + cc) * R + r0 + 8 * k) = o;
    }
}

// ---------------------------------------------------------------------------
// Small 32x32 bf16 transpose (used for V^T only, 2 MB)
// ---------------------------------------------------------------------------
__global__ void transpose32_bf16(const bf16_t* __restrict__ src, bf16_t* __restrict__ dst,
                                 int R, int C, long sStride, long dStride) {
    __shared__ bf16_t tile[32][33];
    src += (long)blockIdx.z * sStride;
    dst += (long)blockIdx.z * dStride;
    const int tx = threadIdx.x & 31, ty = threadIdx.x >> 5;
    const int r0 = blockIdx.y * 32, c0 = blockIdx.x * 32;
#pragma unroll
    for (int i = 0; i < 4; i++) {
        int rr = ty + i * 8;
        tile[rr][tx] = src[(long)(r0 + rr) * C + c0 + tx];
    }
    __syncthreads();
#pragma unroll
    for (int i = 0; i < 4; i++) {
        int cc = ty + i * 8;
        dst[(long)(c0 + cc) * R + r0 + tx] = tile[tx][cc];
    }
}

// ---------------------------------------------------------------------------
// R9 GEMM (R7-verified): BM=BN=128, BK=32, 4 waves, ring-3 LDS, counted
// WAITV(4) + raw s_barrier, pair-XOR swizzle, s_setprio. Unchanged.
// ---------------------------------------------------------------------------
__device__ __forceinline__ void stage_t128(const bf16_t* __restrict__ g, int kt,
                                           bf16_t* sl, int tid) {
#pragma unroll
    for (int c = 0; c < 2; c++) {
        const int chunk = c * 256 + tid;      // 512 chunks: 128 rows x 4
        const int pair = chunk >> 3, P = chunk & 7;
        const int L = P ^ (pair & 7);
        const int row = (pair << 1) | (L >> 2);
        const int cc = L & 3;
        __builtin_amdgcn_global_load_lds((const AS1 void*)(g + (long)row * D_ + kt + cc * 8),
                                         (AS3 void*)(sl + chunk * 8), 16, 0, 0);
    }
}

__device__ __forceinline__ void gstep(const bf16_t* __restrict__ As, const bf16_t* __restrict__ Bs,
                                      bf16_t* Asn, bf16_t* Bsn,
                                      const bf16_t* __restrict__ Ag, const bf16_t* __restrict__ Bg,
                                      int ktn, bool do_stage, int tid,
                                      int wr, int wn, int m16, int quad,
                                      floatx4 acc[4][4]) {
    bf16x8 af[4], bfv[4];
#pragma unroll
    for (int i = 0; i < 4; i++) {
        const int rr = wr * 64 + i * 16 + m16;
        const int L = ((rr & 1) << 2) | quad;
        af[i] = *(const bf16x8*)(As + ((rr >> 1) << 6) + ((L ^ ((rr >> 1) & 7)) << 3));
    }
#pragma unroll
    for (int j = 0; j < 4; j++) {
        const int rr = wn * 64 + j * 16 + m16;
        const int L = ((rr & 1) << 2) | quad;
        bfv[j] = *(const bf16x8*)(Bs + ((rr >> 1) << 6) + ((L ^ ((rr >> 1) & 7)) << 3));
    }
    if (do_stage) {
        stage_t128(Ag, ktn, Asn, tid);
        stage_t128(Bg, ktn, Bsn, tid);
    }
    __builtin_amdgcn_s_setprio(1);
#pragma unroll
    for (int i = 0; i < 4; i++)
#pragma unroll
        for (int j = 0; j < 4; j++) acc[i][j] = MFMA_BF16(af[i], bfv[j], acc[i][j]);
    __builtin_amdgcn_s_setprio(0);
}

#define GSTEP(AS_, BS_, ASN_, BSN_, STG_)                                         \
    WAITV(4); __builtin_amdgcn_s_barrier();                                       \
    gstep(AS_, BS_, ASN_, BSN_, Ag, Bg, kts, STG_, tid, wr, wn, m16, quad, acc);  \
    kts += 32;

template<bool QKV>
__global__ __launch_bounds__(256, 3) void gemm128_kernel(const bf16_t* __restrict__ A,
                                                         const bf16_t* __restrict__ Bt,
                                                         const float* __restrict__ bq,
                                                         const float* __restrict__ bk,
                                                         const float* __restrict__ bv,
                                                         bf16_t* __restrict__ outb,
                                                         float* __restrict__ outf,
                                                         int NT) {
    __shared__ bf16_t As0[128 * 32], As1[128 * 32], As2[128 * 32];
    __shared__ bf16_t Bs0[128 * 32], Bs1[128 * 32], Bs2[128 * 32];

    const int nwg = gridDim.x;
    const int lin = blockIdx.x;
    const int wg = (lin & 7) * (nwg >> 3) + (lin >> 3);   // XCD-chunked (nwg%8==0)
    const int mt = wg / NT, nt = wg % NT;

    const bf16_t* Ag = A + (long)mt * 128 * D_;
    const bf16_t* Bg = Bt + (long)nt * 128 * D_;

    const int tid = threadIdx.x, w = tid >> 6, l = tid & 63;
    const int m16 = l & 15, quad = l >> 4;
    const int wr = w >> 1, wn = w & 1;

    floatx4 acc[4][4];
#pragma unroll
    for (int i = 0; i < 4; i++)
#pragma unroll
        for (int j = 0; j < 4; j++) acc[i][j] = (floatx4){0.f, 0.f, 0.f, 0.f};

    stage_t128(Ag, 0, As0, tid);  stage_t128(Bg, 0, Bs0, tid);
    stage_t128(Ag, 32, As1, tid); stage_t128(Bg, 32, Bs1, tid);
    int kts = 64;

#pragma unroll 1
    for (int g = 0; g < 36; g++) {                 // s = 0..107
        GSTEP(As0, Bs0, As2, Bs2, true)
        GSTEP(As1, Bs1, As0, Bs0, true)
        GSTEP(As2, Bs2, As1, Bs1, true)
    }
    GSTEP(As0, Bs0, As2, Bs2, true)                // s=108
    GSTEP(As1, Bs1, As0, Bs0, true)                // s=109
    WAITV(4); __builtin_amdgcn_s_barrier();
    gstep(As2, Bs2, As0, Bs0, Ag, Bg, 0, false, tid, wr, wn, m16, quad, acc);   // s=110
    WAITV(0); __builtin_amdgcn_s_barrier();
    gstep(As0, Bs0, As1, Bs1, Ag, Bg, 0, false, tid, wr, wn, m16, quad, acc);   // s=111

    if (QKV) {
        const int hd = nt;
        const float* bias = hd < NH_ ? bq + hd * H_
                                     : (hd < NH_ + KV_ ? bk + (hd - NH_) * H_
                                                       : bv + (hd - NH_ - KV_) * H_);
        bf16_t* C = outb + (long)hd * T_ * H_ + (long)(mt * 128) * H_;
#pragma unroll
        for (int j = 0; j < 4; j++) {
            const int col = wn * 64 + j * 16 + m16;
            const float bb = bias[col];
#pragma unroll
            for (int i = 0; i < 4; i++) {
                const int row = wr * 64 + i * 16 + quad * 4;
#pragma unroll
                for (int r = 0; r < 4; r++) C[(long)(row + r) * H_ + col] = (bf16_t)(acc[i][j][r] + bb);
            }
        }
    } else {
        float* C = outf + (long)(mt * 128) * D_ + nt * 128;
#pragma unroll
        for (int j = 0; j < 4; j++) {
            const int col = wn * 64 + j * 16 + m16;
#pragma unroll
            for (int i = 0; i < 4; i++) {
                const int row = wr * 64 + i * 16 + quad * 4;
#pragma unroll
                for (int r = 0; r < 4; r++) C[(long)(row + r) * D_ + col] = acc[i][j][r];
            }
        }
    }
}

// ---------------------------------------------------------------------------
// In-place RoPE; q heads scaled by H^-0.5 * log2e (exp2-domain softmax)
// ---------------------------------------------------------------------------
__global__ void rope_kernel(bf16_t* __restrict__ qkv, const int* __restrict__ pos) {
    const int idx = blockIdx.x * blockDim.x + threadIdx.x;
    const int h = idx & 63;
    const int t = (idx >> 6) & (T_ - 1);
    const int hd = idx >> 17;
    if (hd >= NH_ + KV_) return;
    bf16_t* p = qkv + ((long)hd * T_ + t) * H_;
    const float x1 = (float)p[h], x2 = (float)p[h + 64];
    const float inv = expf(-(float)h * (13.815510557964274f / 64.f));
    const float ang = (float)pos[t] * inv;
    float s, c;
    sincosf(ang, &s, &c);
    float o1 = x1 * c - x2 * s;
    float o2 = x2 * c + x1 * s;
    if (hd < NH_) { o1 *= QSCALE; o2 *= QSCALE; }
    p[h] = (bf16_t)o1;
    p[h + 64] = (bf16_t)o2;
}

// ---------------------------------------------------------------------------
// R9 flash attention: 128-row q-tiles, 448 blocks (16 tiles x 28 heads),
// 8 waves x 16 rows/wave. LPT dispatch (longest tile first). 64 KB LDS ->
// 2 blocks/CU capacity; 448 < 512 => ALL blocks resident from t=0; paired
// blocks are barrier-independent -> 4 waves/SIMD in desynced phases (the
// R8 post-mortem's 73% stall was 2 waves/SIMD in barrier lockstep).
// Same verified loop body: gload_lds pre-swizzled staging, double-buffer
// stage-ahead-1, exp2-domain softmax + defer-max, in-register P shuffle.
// ---------------------------------------------------------------------------
__device__ __forceinline__ void attn_stage9(const bf16_t* __restrict__ Kg,
                                            const bf16_t* __restrict__ Vg,
                                            int sb, int tid,
                                            const int kOff[2], const int vOff[2],
                                            bf16_t* Ks, bf16_t* Vs) {
    const long kBase = (long)sb * 64 * H_;
    const int  vBase = sb * 64;
#pragma unroll
    for (int i = 0; i < 2; i++)
        __builtin_amdgcn_global_load_lds((const AS1 void*)(Kg + kBase + kOff[i]),
                                         (AS3 void*)(Ks + (i * 512 + tid) * 8), 16, 0, 0);
#pragma unroll
    for (int i = 0; i < 2; i++)
        __builtin_amdgcn_global_load_lds((const AS1 void*)(Vg + vBase + vOff[i]),
                                         (AS3 void*)(Vs + (i * 512 + tid) * 8), 16, 0, 0);
}

__device__ __forceinline__ void attn_step9(const bf16_t* __restrict__ Ks,
                                           const bf16_t* __restrict__ Vs,
                                           int sb, int q0, int m16, int quad,
                                           int s0, int s1, bool hiq,
                                           const bf16x8 qf[4], floatx4 ot[8],
                                           float& mi, float& li) {
    // S^T[s=64][q=16]: 4 ts tiles, K fragments from swizzled LDS
    floatx4 stv[4];
    __builtin_amdgcn_s_setprio(1);
#pragma unroll
    for (int ts = 0; ts < 4; ts++) {
        bf16x8 kf[4];
#pragma unroll
        for (int kk = 0; kk < 4; kk++)
            kf[kk] = *(const bf16x8*)(Ks + (16 * ts + m16) * 128 +
                                      ((((kk << 2) + quad) ^ (m16 & 7)) << 3));
        floatx4 c = (floatx4){0.f, 0.f, 0.f, 0.f};
#pragma unroll
        for (int kk = 0; kk < 4; kk++) c = MFMA_BF16(kf[kk], qf[kk], c);
        stv[ts] = c;
    }
    __builtin_amdgcn_s_setprio(0);

    // online softmax (exp2 domain, defer-max); pack P to bf16 words
    unsigned int W[4][2];
    const int qg = q0 + m16;
    if ((sb * 64 + 63) > q0) {
#pragma unroll
        for (int ts = 0; ts < 4; ts++)
#pragma unroll
            for (int r = 0; r < 4; r++) {
                const int sg = sb * 64 + ts * 16 + quad * 4 + r;
                if (sg > qg) stv[ts][r] = -1e30f;
            }
    }
    float mx = -1e30f;
#pragma unroll
    for (int ts = 0; ts < 4; ts++)
#pragma unroll
        for (int r = 0; r < 4; r++) mx = fmaxf(mx, stv[ts][r]);
    mx = fmaxf(mx, __shfl_xor(mx, 16));
    mx = fmaxf(mx, __shfl_xor(mx, 32));
    float mn = mi;
    if (__any(mx > mi + 8.f)) {                  // defer-max (T13)
        mn = fmaxf(mi, mx);
        const float alpha = exp2f(mi - mn);
        mi = mn;
        li *= alpha;
#pragma unroll
        for (int ht = 0; ht < 8; ht++) ot[ht] *= alpha;
    }
    float rs = 0.f;
#pragma unroll
    for (int ts = 0; ts < 4; ts++) {
        const float p0 = exp2f(stv[ts][0] - mn);
        const float p1 = exp2f(stv[ts][1] - mn);
        const float p2 = exp2f(stv[ts][2] - mn);
        const float p3 = exp2f(stv[ts][3] - mn);
        rs += p0 + p1 + p2 + p3;
        bf16x4 pv = {(bf16_t)p0, (bf16_t)p1, (bf16_t)p2, (bf16_t)p3};
        uint2_ u = __builtin_bit_cast(uint2_, pv);
        W[ts][0] = u.x;
        W[ts][1] = u.y;
    }
    rs += __shfl_xor(rs, 16);
    rs += __shfl_xor(rs, 32);
    li += rs;

    // O^T[h][q=16] += V^T[h][s] P^T[s][q]; P redistributed via shfl
#pragma unroll
    for (int ck = 0; ck < 2; ck++) {
        const unsigned a0 = W[2 * ck][0], a1 = W[2 * ck][1];
        const unsigned b0 = W[2 * ck + 1][0], b1 = W[2 * ck + 1][1];
        unsigned pw0, pw1, pw2, pw3;
        { const unsigned xa = __shfl((int)a0, s0), xb = __shfl((int)b0, s0); pw0 = hiq ? xb : xa; }
        { const unsigned xa = __shfl((int)a1, s0), xb = __shfl((int)b1, s0); pw1 = hiq ? xb : xa; }
        { const unsigned xa = __shfl((int)a0, s1), xb = __shfl((int)b0, s1); pw2 = hiq ? xb : xa; }
        { const unsigned xa = __shfl((int)a1, s1), xb = __shfl((int)b1, s1); pw3 = hiq ? xb : xa; }
        uint4_ pv4 = {pw0, pw1, pw2, pw3};
        const bf16x8 pf = __builtin_bit_cast(bf16x8, pv4);
        __builtin_amdgcn_s_setprio(1);
#pragma unroll
        for (int ht = 0; ht < 8; ht++) {
            bf16x8 vf = *(const bf16x8*)(Vs + (16 * ht + m16) * 64 +
                                         ((((ck << 2) + quad) ^ (m16 & 7)) << 3));
            ot[ht] = MFMA_BF16(vf, pf, ot[ht]);
        }
        __builtin_amdgcn_s_setprio(0);
    }
}

__global__ __launch_bounds__(512) void attn_kernel(const bf16_t* __restrict__ qkv,
                                                   const bf16_t* __restrict__ vT,
                                                   bf16_t* __restrict__ ctx) {
    __shared__ bf16_t smem[32768];               // K0|K1|V0|V1, 16 KB each = 64 KB
    bf16_t* K0 = smem;
    bf16_t* K1 = smem + 8192;
    bf16_t* V0 = smem + 16384;
    bf16_t* V1 = smem + 24576;

    const int b = blockIdx.x;
    const int jt = 15 - (b / NH_);               // LPT: longest q-tiles dispatch first
    const int n  = b % NH_;
    const int kvh = n / 7;
    const bf16_t* Q  = qkv + (long)n * T_ * H_;
    const bf16_t* Kg = qkv + (long)(NH_ + kvh) * T_ * H_;
    const bf16_t* Vg = vT + (long)kvh * H_ * T_;   // [h][t]

    const int tid = threadIdx.x, w = tid >> 6, l = tid & 63;
    const int m16 = l & 15, quad = l >> 4;
    const int q0 = jt * 128 + w * 16;            // this wave's 16 rows

    // Pre-swizzled global source offsets; LDS dest linear (chunk*16B).
    int kOff[2], vOff[2];
#pragma unroll
    for (int i = 0; i < 2; i++) {
        const int ck_ = i * 512 + tid;           // K: 64 rows x 16 chunks = 1024
        const int kr = ck_ >> 4, kc = ck_ & 15;
        kOff[i] = kr * H_ + ((kc ^ (kr & 7)) << 3);
        const int vr = ck_ >> 3, vc = ck_ & 7;   // V: 128 rows x 8 chunks = 1024
        vOff[i] = vr * T_ + ((vc ^ (vr & 7)) << 3);
    }

    bf16x8 qf[4];
#pragma unroll
    for (int kk = 0; kk < 4; kk++)
        qf[kk] = *(const bf16x8*)(Q + (long)(q0 + m16) * H_ + kk * 32 + quad * 8);

    floatx4 ot[8];
#pragma unroll
    for (int ht = 0; ht < 8; ht++) ot[ht] = (floatx4){0.f, 0.f, 0.f, 0.f};
    float mi = -1e30f, li = 0.f;

    const int s0 = m16 + ((quad & 1) << 5);
    const int s1 = s0 + 16;
    const bool hiq = (quad & 2) != 0;

    const int E = 2 * jt + 2;                    // block-uniform trip count
    const int sbEw = (q0 + 79) >> 6;             // this wave's causal end (rows q0..q0+15)

    attn_stage9(Kg, Vg, 0, tid, kOff, vOff, K0, V0);
    int sb = 0;
    while (true) {
        __syncthreads();                         // drains stage(sb) DMA; orders buf reuse
        if (sb + 1 < E) attn_stage9(Kg, Vg, sb + 1, tid, kOff, vOff, K1, V1);
        if (sb < sbEw) attn_step9(K0, V0, sb, q0, m16, quad, s0, s1, hiq, qf, ot, mi, li);
        if (++sb >= E) break;
        __syncthreads();
        if (sb + 1 < E) attn_stage9(Kg, Vg, sb + 1, tid, kOff, vOff, K0, V0);
        if (sb < sbEw) attn_step9(K1, V1, sb, q0, m16, quad, s0, s1, hiq, qf, ot, mi, li);
        if (++sb >= E) break;
    }
    __syncthreads();                             // all waves done before smem reuse

    // Epilogue: normalize, per-wave swizzled transpose (4 KB slice), direct ctx write
    const float inv = 1.f / li;
    bf16_t* Oq = smem + w * 2048;                // 16 rows x 128 cols x 2B = 4 KB
    {
        const int r = m16;
#pragma unroll
        for (int ht = 0; ht < 8; ht++) {
            bf16x4 v = {(bf16_t)(ot[ht][0] * inv), (bf16_t)(ot[ht][1] * inv),
                        (bf16_t)(ot[ht][2] * inv), (bf16_t)(ot[ht][3] * inv)};
            const int chunk = (2 * ht + (quad >> 1)) ^ (r & 7);
            *(bf16x4*)((char*)Oq + r * 256 + (chunk << 4) + ((quad & 1) << 3)) = v;
        }
    }
    {
        const int qrow = l >> 2, q4 = l & 3;     // 16 rows x 4 col-quarters
        bf16_t* dst = ctx + (long)(q0 + qrow) * (NH_ * H_) + n * H_ + q4 * 32;
#pragma unroll
        for (int j = 0; j < 4; j++) {
            const int chunk = (q4 * 4 + j) ^ (qrow & 7);
            const bf16x8 o = *(const bf16x8*)((char*)Oq + qrow * 256 + (chunk << 4));
            *(bf16x8*)(dst + j * 8) = o;
        }
    }
}

// ---------------------------------------------------------------------------
extern "C" void kernel_launch(void* const* d_in, const int* in_sizes, int n_in,
                              void* d_out, int out_size, void* d_ws, size_t ws_size,
                              hipStream_t stream) {
    const float* x  = (const float*)d_in[0];
    const int*   ps = (const int*)d_in[1];
    const float* wq = (const float*)d_in[2];
    const float* bq = (const float*)d_in[3];
    const float* wk = (const float*)d_in[4];
    const float* bk = (const float*)d_in[5];
    const float* wv = (const float*)d_in[6];
    const float* bv = (const float*)d_in[7];
    const float* wo = (const float*)d_in[8];
    float* out = (float*)d_out;

    bf16_t* xb  = (bf16_t*)d_ws;                 // [2048][3584]    x in bf16
    bf16_t* wt  = xb + (long)T_ * D_;            // [36][128][3584] transposed qkv weights
    bf16_t* woT = wt + (long)NW_ * H_ * D_;      // [3584][3584]    woT[d][n*H+h]
    bf16_t* qkv = woT + (long)D_ * D_;           // [36][2048][128] projections
    bf16_t* vT  = qkv + (long)NW_ * T_ * H_;     // [4][128][2048]  V transposed
    bf16_t* ctx = vT + (long)KV_ * H_ * T_;      // [2048][3584]    attention output (bf16)

    const long whd = (long)D_ * H_;
    convert_f32_bf16<<<((long)T_ * D_ / 8 + 255) / 256, 256, 0, stream>>>(x, xb);
    transpose64_f32_bf16<<<dim3(H_ / 64, D_ / 64, NH_), 256, 0, stream>>>(wq, wt, D_, H_, whd, whd);
    transpose64_f32_bf16<<<dim3(H_ / 64, D_ / 64, KV_), 256, 0, stream>>>(wk, wt + (long)NH_ * whd, D_, H_, whd, whd);
    transpose64_f32_bf16<<<dim3(H_ / 64, D_ / 64, KV_), 256, 0, stream>>>(wv, wt + (long)(NH_ + KV_) * whd, D_, H_, whd, whd);
    transpose64_f32_bf16<<<dim3(D_ / 64, D_ / 64, 1), 256, 0, stream>>>(wo, woT, D_, D_, 0, 0);

    gemm128_kernel<true><<<dim3(T_ / 128 * NW_), 256, 0, stream>>>(xb, wt, bq, bk, bv, qkv, nullptr, NW_);
    rope_kernel<<<(32 * T_ * 64) / 256, 256, 0, stream>>>(qkv, ps);
    transpose32_bf16<<<dim3(H_ / 32, T_ / 32, KV_), 256, 0, stream>>>(qkv + (long)(NH_ + KV_) * T_ * H_, vT,
                                                                      T_, H_, (long)T_ * H_, (long)T_ * H_);
    attn_kernel<<<dim3(16 * NH_), 512, 0, stream>>>(qkv, vT, ctx);
    gemm128_kernel<false><<<dim3(T_ / 128 * (D_ / 128)), 256, 0, stream>>>(ctx, woT, nullptr, nullptr, nullptr,
                                                                           nullptr, out, D_ / 128);
}